// Round 2
// baseline (446.837 us; speedup 1.0000x reference)
//
#include <hip/hip_runtime.h>
#include <hip/hip_bf16.h>
#include <stdint.h>

#define B_ 4
#define S_ 2048
#define D_ 1024
#define H_ 16
#define DK_ 64

typedef __hip_bfloat16 bf16;
typedef __attribute__((ext_vector_type(8))) __bf16 bf16x8;
typedef __attribute__((ext_vector_type(4))) __bf16 bf16x4;
typedef __attribute__((ext_vector_type(4))) float f32x4;
typedef __attribute__((ext_vector_type(4))) uint32_t u32x4;

// scale 1/sqrt(DK) folded with log2(e): Q pre-scaled so p = exp2(S^T) directly
#define QSCALE 0.18033688011112042f   // 0.125 * 1.4426950408889634

#if defined(__has_builtin)
#if __has_builtin(__builtin_amdgcn_exp2f)
#define EXP2(x) __builtin_amdgcn_exp2f(x)
#endif
#endif
#ifndef EXP2
#define EXP2(x) exp2f(x)
#endif

__device__ __forceinline__ void async_copy16(const void* g, void* l) {
    __builtin_amdgcn_global_load_lds((const __attribute__((address_space(1))) void*)g,
                                     (__attribute__((address_space(3))) void*)l,
                                     16, 0, 0);
}

__device__ __forceinline__ bf16x8 ld8(const bf16* p) {
    return *(const bf16x8*)p;
}

__device__ __forceinline__ uint32_t pk2(float a, float b) {
    union { __bf16 h; uint16_t u; } x, y;
    x.h = (__bf16)a; y.h = (__bf16)b;
    return (uint32_t)x.u | ((uint32_t)y.u << 16);
}

__device__ __forceinline__ bf16x8 cvt8(float4 u0, float4 u1) {
    return (bf16x8){(__bf16)u0.x, (__bf16)u0.y, (__bf16)u0.z, (__bf16)u0.w,
                    (__bf16)u1.x, (__bf16)u1.y, (__bf16)u1.z, (__bf16)u1.w};
}

// C-layout 16x32 P-tile (two 16x16 subtiles p0,p1) -> B-fragment of P^T (k=32, n=16)
__device__ __forceinline__ bf16x8 transpose_p(const float* p0, const float* p1,
                                              int srcl, bool loT) {
    uint32_t x0 = pk2(p0[0], p0[1]), x1 = pk2(p0[2], p0[3]);
    uint32_t y0 = pk2(p1[0], p1[1]), y1 = pk2(p1[2], p1[3]);
    u32x4 dw;
#pragma unroll
    for (int i = 0; i < 4; i++) {
        int sl = srcl + (i >> 1) * 16;
        uint32_t vA = (uint32_t)__shfl((int)((i & 1) ? x1 : x0), sl, 64);
        uint32_t vB = (uint32_t)__shfl((int)((i & 1) ? y1 : y0), sl, 64);
        dw[i] = loT ? vA : vB;
    }
    return __builtin_bit_cast(bf16x8, dw);
}

// convert the 4 weight matrices f32->bf16 in one launch (4 x 262144 float4)
__global__ __launch_bounds__(256) void cvtw(const float4* __restrict__ s0,
                                            const float4* __restrict__ s1,
                                            const float4* __restrict__ s2,
                                            const float4* __restrict__ s3,
                                            bf16x4* __restrict__ d0,
                                            bf16x4* __restrict__ d1,
                                            bf16x4* __restrict__ d2,
                                            bf16x4* __restrict__ d3) {
    int i = blockIdx.x * 256 + threadIdx.x;
    int seg = i >> 18;            // 262144 float4 per matrix
    int j   = i & 262143;
    const float4* s = seg == 0 ? s0 : seg == 1 ? s1 : seg == 2 ? s2 : s3;
    bf16x4*       d = seg == 0 ? d0 : seg == 1 ? d1 : seg == 2 ? d2 : d3;
    float4 f = s[j];
    d[j] = (bf16x4){(__bf16)f.x, (__bf16)f.y, (__bf16)f.z, (__bf16)f.w};
}

// one-shot activation conversion f32 -> bf16 (q,k,v), 8 elems / thread
__global__ __launch_bounds__(256) void cvtx(const float* __restrict__ s0,
                                            const float* __restrict__ s1,
                                            const float* __restrict__ s2,
                                            bf16* __restrict__ d0,
                                            bf16* __restrict__ d1,
                                            bf16* __restrict__ d2) {
    const int z = blockIdx.z;
    const float* s = z == 0 ? s0 : z == 1 ? s1 : s2;
    bf16*        d = z == 0 ? d0 : z == 1 ? d1 : d2;
    size_t i = ((size_t)blockIdx.x * 256 + threadIdx.x) * 8;
    float4 u0 = *(const float4*)(s + i);
    float4 u1 = *(const float4*)(s + i + 4);
    *(bf16x8*)(d + i) = cvt8(u0, u1);
}

// Pure-bf16 fused Q/K/V projection (m97 structure: dual global_load_lds staging).
// z=0: Q (scaled, layout [bh][s][dk]); z=1: K (same layout); z=2: V (transposed [bh][dk][s]).
__global__ __launch_bounds__(256) void gemm_qkv_bf(const bf16* __restrict__ Aq,
                                                   const bf16* __restrict__ Ak,
                                                   const bf16* __restrict__ Av,
                                                   const bf16* __restrict__ Wqb,
                                                   const bf16* __restrict__ Wkb,
                                                   const bf16* __restrict__ Wvb,
                                                   bf16* __restrict__ Oq,
                                                   bf16* __restrict__ Ok,
                                                   bf16* __restrict__ Ov) {
    __shared__ bf16 lA[128 * 32];
    __shared__ bf16 lW[128 * 32];
    const int z = blockIdx.z;
    const bf16* A = z == 0 ? Aq : z == 1 ? Ak : Av;
    const bf16* W = z == 0 ? Wqb : z == 1 ? Wkb : Wvb;
    bf16*      out = z == 0 ? Oq : z == 1 ? Ok : Ov;

    const int tid  = threadIdx.x;
    const int lane = tid & 63;
    const int quad = lane >> 4;
    const int lo   = lane & 15;
    const int wave = tid >> 6;
    const int wm   = (wave >> 1) * 64;
    const int wn   = (wave & 1) * 64;
    const int n0   = blockIdx.x * 128;
    const int m0   = blockIdx.y * 128;
    const int K    = 1024;

    f32x4 acc[4][4];
#pragma unroll
    for (int i = 0; i < 4; i++)
#pragma unroll
        for (int j = 0; j < 4; j++) acc[i][j] = (f32x4){0.f, 0.f, 0.f, 0.f};

    const int sr = tid >> 2;
    const int sc = (tid & 3) * 8;

    for (int k0 = 0; k0 < K; k0 += 32) {
        async_copy16(A + (size_t)(m0 + sr) * K + k0 + sc,       lA + sr * 32 + sc);
        async_copy16(A + (size_t)(m0 + 64 + sr) * K + k0 + sc,  lA + (64 + sr) * 32 + sc);
        async_copy16(W + (size_t)(n0 + sr) * K + k0 + sc,       lW + sr * 32 + sc);
        async_copy16(W + (size_t)(n0 + 64 + sr) * K + k0 + sc,  lW + (64 + sr) * 32 + sc);
        __syncthreads();

        bf16x8 af[4], bfr[4];
#pragma unroll
        for (int i = 0; i < 4; i++)
            af[i] = ld8(lA + (wm + i * 16 + lo) * 32 + quad * 8);
#pragma unroll
        for (int j = 0; j < 4; j++)
            bfr[j] = ld8(lW + (wn + j * 16 + lo) * 32 + quad * 8);
#pragma unroll
        for (int i = 0; i < 4; i++)
#pragma unroll
            for (int j = 0; j < 4; j++)
                acc[i][j] = __builtin_amdgcn_mfma_f32_16x16x32_bf16(af[i], bfr[j], acc[i][j], 0, 0, 0);
        __syncthreads();
    }

#pragma unroll
    for (int i = 0; i < 4; i++)
#pragma unroll
        for (int j = 0; j < 4; j++)
#pragma unroll
            for (int r = 0; r < 4; r++) {
                int m = m0 + wm + i * 16 + quad * 4 + r;
                int n = n0 + wn + j * 16 + lo;
                float val = acc[i][j][r];
                int b = m >> 11, s = m & (S_ - 1);
                int h = n >> 6, dk = n & 63;
                if (z == 0) {
                    out[((size_t)(b * H_ + h) * S_ + s) * DK_ + dk] =
                        __float2bfloat16(val * QSCALE);
                } else if (z == 1) {
                    out[((size_t)(b * H_ + h) * S_ + s) * DK_ + dk] = __float2bfloat16(val);
                } else {
                    out[((size_t)(b * H_ + h) * DK_ + dk) * S_ + s] = __float2bfloat16(val);
                }
            }
}

// Fallback (small workspace): fused in-register f32->bf16 conversion path.
__global__ __launch_bounds__(256) void gemm_qkv(const float* __restrict__ Aq,
                                                const float* __restrict__ Ak,
                                                const float* __restrict__ Av,
                                                const bf16* __restrict__ Wqb,
                                                const bf16* __restrict__ Wkb,
                                                const bf16* __restrict__ Wvb,
                                                bf16* __restrict__ Oq,
                                                bf16* __restrict__ Ok,
                                                bf16* __restrict__ Ov) {
    __shared__ bf16 lA[128 * 32];
    __shared__ bf16 lW[128 * 32];
    const int z = blockIdx.z;
    const float* A = z == 0 ? Aq : z == 1 ? Ak : Av;
    const bf16*  W = z == 0 ? Wqb : z == 1 ? Wkb : Wvb;
    bf16*      out = z == 0 ? Oq : z == 1 ? Ok : Ov;

    const int tid  = threadIdx.x;
    const int lane = tid & 63;
    const int quad = lane >> 4;
    const int lo   = lane & 15;
    const int wave = tid >> 6;
    const int wm   = (wave >> 1) * 64;
    const int wn   = (wave & 1) * 64;
    const int n0   = blockIdx.x * 128;
    const int m0   = blockIdx.y * 128;
    const int K    = 1024;

    f32x4 acc[4][4];
#pragma unroll
    for (int i = 0; i < 4; i++)
#pragma unroll
        for (int j = 0; j < 4; j++) acc[i][j] = (f32x4){0.f, 0.f, 0.f, 0.f};

    const int sr = tid >> 2;
    const int sc = (tid & 3) * 8;

    for (int k0 = 0; k0 < K; k0 += 32) {
        async_copy16(W + (size_t)(n0 + sr) * K + k0 + sc,       lW + sr * 32 + sc);
        async_copy16(W + (size_t)(n0 + 64 + sr) * K + k0 + sc,  lW + (64 + sr) * 32 + sc);
        const float* a0 = A + (size_t)(m0 + sr) * K + k0 + sc;
        const float* a1 = A + (size_t)(m0 + 64 + sr) * K + k0 + sc;
        float4 u0 = *(const float4*)a0;
        float4 u1 = *(const float4*)(a0 + 4);
        float4 u2 = *(const float4*)a1;
        float4 u3 = *(const float4*)(a1 + 4);
        *(bf16x8*)(lA + sr * 32 + sc)        = cvt8(u0, u1);
        *(bf16x8*)(lA + (64 + sr) * 32 + sc) = cvt8(u2, u3);
        __syncthreads();

        bf16x8 af[4], bfr[4];
#pragma unroll
        for (int i = 0; i < 4; i++)
            af[i] = ld8(lA + (wm + i * 16 + lo) * 32 + quad * 8);
#pragma unroll
        for (int j = 0; j < 4; j++)
            bfr[j] = ld8(lW + (wn + j * 16 + lo) * 32 + quad * 8);
#pragma unroll
        for (int i = 0; i < 4; i++)
#pragma unroll
            for (int j = 0; j < 4; j++)
                acc[i][j] = __builtin_amdgcn_mfma_f32_16x16x32_bf16(af[i], bfr[j], acc[i][j], 0, 0, 0);
        __syncthreads();
    }

#pragma unroll
    for (int i = 0; i < 4; i++)
#pragma unroll
        for (int j = 0; j < 4; j++)
#pragma unroll
            for (int r = 0; r < 4; r++) {
                int m = m0 + wm + i * 16 + quad * 4 + r;
                int n = n0 + wn + j * 16 + lo;
                float val = acc[i][j][r];
                int b = m >> 11, s = m & (S_ - 1);
                int h = n >> 6, dk = n & 63;
                if (z == 0) {
                    out[((size_t)(b * H_ + h) * S_ + s) * DK_ + dk] =
                        __float2bfloat16(val * QSCALE);
                } else if (z == 1) {
                    out[((size_t)(b * H_ + h) * S_ + s) * DK_ + dk] = __float2bfloat16(val);
                } else {
                    out[((size_t)(b * H_ + h) * DK_ + dk) * S_ + s] = __float2bfloat16(val);
                }
            }
}

// Final projection: A bf16 (attn output X), W bf16, out float32 [8192 x 1024]
__global__ __launch_bounds__(256) void gemm_out(const bf16* __restrict__ A,
                                                const bf16* __restrict__ W,
                                                float* __restrict__ out) {
    __shared__ bf16 lA[128 * 32];
    __shared__ bf16 lW[128 * 32];
    const int tid  = threadIdx.x;
    const int lane = tid & 63;
    const int quad = lane >> 4;
    const int lo   = lane & 15;
    const int wave = tid >> 6;
    const int wm   = (wave >> 1) * 64;
    const int wn   = (wave & 1) * 64;
    const int n0   = blockIdx.x * 128;
    const int m0   = blockIdx.y * 128;
    const int K    = 1024;

    f32x4 acc[4][4];
#pragma unroll
    for (int i = 0; i < 4; i++)
#pragma unroll
        for (int j = 0; j < 4; j++) acc[i][j] = (f32x4){0.f, 0.f, 0.f, 0.f};

    const int sr = tid >> 2;
    const int sc = (tid & 3) * 8;

    for (int k0 = 0; k0 < K; k0 += 32) {
        async_copy16(A + (size_t)(m0 + sr) * K + k0 + sc,       lA + sr * 32 + sc);
        async_copy16(A + (size_t)(m0 + 64 + sr) * K + k0 + sc,  lA + (64 + sr) * 32 + sc);
        async_copy16(W + (size_t)(n0 + sr) * K + k0 + sc,       lW + sr * 32 + sc);
        async_copy16(W + (size_t)(n0 + 64 + sr) * K + k0 + sc,  lW + (64 + sr) * 32 + sc);
        __syncthreads();

        bf16x8 af[4], bfr[4];
#pragma unroll
        for (int i = 0; i < 4; i++)
            af[i] = ld8(lA + (wm + i * 16 + lo) * 32 + quad * 8);
#pragma unroll
        for (int j = 0; j < 4; j++)
            bfr[j] = ld8(lW + (wn + j * 16 + lo) * 32 + quad * 8);
#pragma unroll
        for (int i = 0; i < 4; i++)
#pragma unroll
            for (int j = 0; j < 4; j++)
                acc[i][j] = __builtin_amdgcn_mfma_f32_16x16x32_bf16(af[i], bfr[j], acc[i][j], 0, 0, 0);
        __syncthreads();
    }

#pragma unroll
    for (int i = 0; i < 4; i++)
#pragma unroll
        for (int j = 0; j < 4; j++)
#pragma unroll
            for (int r = 0; r < 4; r++) {
                int m = m0 + wm + i * 16 + quad * 4 + r;
                int n = n0 + wn + j * 16 + lo;
                out[(size_t)m * D_ + n] = acc[i][j][r];
            }
}

// ---------------- attention helpers (software-pipelined) ----------------

__device__ __forceinline__ void loadK4(const bf16* __restrict__ Kp, int kv, int lo, int quad,
                                       bf16x8& k0, bf16x8& k1, bf16x8& k2, bf16x8& k3) {
    const bf16* kn = Kp + (size_t)(kv + lo) * DK_ + quad * 8;
    k0 = ld8(kn);
    k1 = ld8(kn + 32);
    k2 = ld8(kn + 16 * DK_);
    k3 = ld8(kn + 16 * DK_ + 32);
}

__device__ __forceinline__ void qk8(const bf16x8& k0, const bf16x8& k1,
                                    const bf16x8& k2, const bf16x8& k3,
                                    const bf16x8& bQa0, const bf16x8& bQa1,
                                    const bf16x8& bQb0, const bf16x8& bQb1,
                                    f32x4& s0, f32x4& s1, f32x4& s2, f32x4& s3) {
    s0 = (f32x4){0.f, 0.f, 0.f, 0.f};
    s1 = (f32x4){0.f, 0.f, 0.f, 0.f};
    s2 = (f32x4){0.f, 0.f, 0.f, 0.f};
    s3 = (f32x4){0.f, 0.f, 0.f, 0.f};
    s0 = __builtin_amdgcn_mfma_f32_16x16x32_bf16(k0, bQa0, s0, 0, 0, 0);
    s0 = __builtin_amdgcn_mfma_f32_16x16x32_bf16(k1, bQa1, s0, 0, 0, 0);
    s1 = __builtin_amdgcn_mfma_f32_16x16x32_bf16(k2, bQa0, s1, 0, 0, 0);
    s1 = __builtin_amdgcn_mfma_f32_16x16x32_bf16(k3, bQa1, s1, 0, 0, 0);
    s2 = __builtin_amdgcn_mfma_f32_16x16x32_bf16(k0, bQb0, s2, 0, 0, 0);
    s2 = __builtin_amdgcn_mfma_f32_16x16x32_bf16(k1, bQb1, s2, 0, 0, 0);
    s3 = __builtin_amdgcn_mfma_f32_16x16x32_bf16(k2, bQb0, s3, 0, 0, 0);
    s3 = __builtin_amdgcn_mfma_f32_16x16x32_bf16(k3, bQb1, s3, 0, 0, 0);
}

__device__ __forceinline__ void sfpv(int it, int nfull, const bf16* __restrict__ Vp,
                                     int lo, int quad, int srcl, bool loT,
                                     const f32x4& s0, const f32x4& s1,
                                     const f32x4& s2, const f32x4& s3,
                                     f32x4 (&outA)[4], f32x4 (&outB)[4],
                                     float& lsumA, float& lsumB) {
    const int kv0 = it * 32;
    const bool masked = (it == nfull);

    bf16x8 aV[4];
#pragma unroll
    for (int t = 0; t < 4; t++)
        aV[t] = ld8(Vp + (size_t)(t * 16 + lo) * S_ + kv0 + quad * 8);

    float pA0[4], pA1[4], pB0[4], pB1[4];
#pragma unroll
    for (int r = 0; r < 4; r++) {
        float eA0 = EXP2(s0[r]);
        float eA1 = EXP2(s1[r]);
        float eB0 = EXP2(s2[r]);
        float eB1 = EXP2(s3[r]);
        if (masked) {
            bool c = (quad * 4 + r) <= lo;
            eA0 = c ? eA0 : 0.f;
            eA1 = 0.f;
            eB1 = c ? eB1 : 0.f;
        }
        pA0[r] = eA0; pA1[r] = eA1; pB0[r] = eB0; pB1[r] = eB1;
        lsumA += eA0 + eA1;
        lsumB += eB0 + eB1;
    }

    bf16x8 bPA = transpose_p(pA0, pA1, srcl, loT);
    bf16x8 bPB = transpose_p(pB0, pB1, srcl, loT);

#pragma unroll
    for (int t = 0; t < 4; t++) {
        outA[t] = __builtin_amdgcn_mfma_f32_16x16x32_bf16(aV[t], bPA, outA[t], 0, 0, 0);
        outB[t] = __builtin_amdgcn_mfma_f32_16x16x32_bf16(aV[t], bPB, outB[t], 0, 0, 0);
    }
}

// Transposed flash attention, causal, no-max softmax. 1 wave / 32 q rows.
// Software-pipelined: QK^T(t+1) issued BEFORE softmax(t) so the exp/transpose
// VALU chain of tile t overlaps the matrix-pipe time of tile t+1.
__global__ __launch_bounds__(64, 4) void attn(const bf16* __restrict__ Q,
                                              const bf16* __restrict__ K,
                                              const bf16* __restrict__ Vt,
                                              bf16* __restrict__ X) {
    const int lane = threadIdx.x;
    const int quad = lane >> 4;
    const int lo   = lane & 15;
    const int idx  = blockIdx.x;
    const int bh   = idx & 63;          // XCD locality: one head stays on one XCD
    const int qb   = 63 - (idx >> 6);   // LPT: longest q-blocks dispatched first
    const int q0   = qb * 32;

    const bf16* Qp = Q  + (size_t)bh * S_ * DK_;
    const bf16* Kp = K  + (size_t)bh * S_ * DK_;
    const bf16* Vp = Vt + (size_t)bh * DK_ * S_;

    bf16x8 bQa0 = ld8(Qp + (size_t)(q0 + lo) * DK_ + quad * 8);
    bf16x8 bQa1 = ld8(Qp + (size_t)(q0 + lo) * DK_ + 32 + quad * 8);
    bf16x8 bQb0 = ld8(Qp + (size_t)(q0 + 16 + lo) * DK_ + quad * 8);
    bf16x8 bQb1 = ld8(Qp + (size_t)(q0 + 16 + lo) * DK_ + 32 + quad * 8);

    f32x4 outA[4], outB[4];
#pragma unroll
    for (int t = 0; t < 4; t++) {
        outA[t] = (f32x4){0.f, 0.f, 0.f, 0.f};
        outB[t] = (f32x4){0.f, 0.f, 0.f, 0.f};
    }
    float lsumA = 0.f, lsumB = 0.f;

    const int nfull = qb;
    const int NT    = nfull + 1;        // number of kv tiles (last one masked)
    const int srcl  = (quad & 1) * 32 + lo;
    const bool loT  = (quad < 2);

    // double-buffered K fragments and score accumulators (named sets, rule #20)
    bf16x8 kE0, kE1, kE2, kE3, kO0, kO1, kO2, kO3;
    f32x4 sE0, sE1, sE2, sE3, sO0, sO1, sO2, sO3;

    loadK4(Kp, 0, lo, quad, kE0, kE1, kE2, kE3);
    qk8(kE0, kE1, kE2, kE3, bQa0, bQa1, bQb0, bQb1, sE0, sE1, sE2, sE3);   // tile 0
    loadK4(Kp, (NT > 1 ? 32 : 0), lo, quad, kO0, kO1, kO2, kO3);           // K(1)

    for (int it = 0; it < NT; it += 2) {
        // even tile `it`: scores in sE, K(it+1) in kO
        qk8(kO0, kO1, kO2, kO3, bQa0, bQa1, bQb0, bQb1, sO0, sO1, sO2, sO3); // tile it+1
        {
            int kv2 = it + 2; if (kv2 > nfull) kv2 = nfull;
            loadK4(Kp, kv2 * 32, lo, quad, kE0, kE1, kE2, kE3);              // K(it+2)
        }
        sfpv(it, nfull, Vp, lo, quad, srcl, loT, sE0, sE1, sE2, sE3,
             outA, outB, lsumA, lsumB);
        if (it + 1 >= NT) break;

        // odd tile `it+1`: scores in sO, K(it+2) in kE
        qk8(kE0, kE1, kE2, kE3, bQa0, bQa1, bQb0, bQb1, sE0, sE1, sE2, sE3); // tile it+2
        {
            int kv3 = it + 3; if (kv3 > nfull) kv3 = nfull;
            loadK4(Kp, kv3 * 32, lo, quad, kO0, kO1, kO2, kO3);              // K(it+3)
        }
        sfpv(it + 1, nfull, Vp, lo, quad, srcl, loT, sO0, sO1, sO2, sO3,
             outA, outB, lsumA, lsumB);
    }

    lsumA += __shfl_xor(lsumA, 16, 64);
    lsumA += __shfl_xor(lsumA, 32, 64);
    lsumB += __shfl_xor(lsumB, 16, 64);
    lsumB += __shfl_xor(lsumB, 32, 64);
    const float rlA = 1.f / lsumA;
    const float rlB = 1.f / lsumB;

    const int b = bh >> 4, h = bh & 15;
    bf16* XpA = X + (size_t)(b * S_ + q0 + lo) * D_ + h * 64;
    bf16* XpB = XpA + (size_t)16 * D_;
#pragma unroll
    for (int t = 0; t < 4; t++) {
        uint32_t* dA = (uint32_t*)(XpA + t * 16 + quad * 4);
        dA[0] = pk2(outA[t][0] * rlA, outA[t][1] * rlA);
        dA[1] = pk2(outA[t][2] * rlA, outA[t][3] * rlA);
        uint32_t* dB = (uint32_t*)(XpB + t * 16 + quad * 4);
        dB[0] = pk2(outB[t][0] * rlB, outB[t][1] * rlB);
        dB[1] = pk2(outB[t][2] * rlB, outB[t][3] * rlB);
    }
}

extern "C" void kernel_launch(void* const* d_in, const int* in_sizes, int n_in,
                              void* d_out, int out_size, void* d_ws, size_t ws_size,
                              hipStream_t stream) {
    const float* q  = (const float*)d_in[0];
    const float* k  = (const float*)d_in[1];
    const float* v  = (const float*)d_in[2];
    const float* wq = (const float*)d_in[4];
    const float* wk = (const float*)d_in[5];
    const float* wv = (const float*)d_in[6];
    const float* wo = (const float*)d_in[7];

    const size_t elems  = (size_t)B_ * S_ * D_;   // 8388608
    const size_t welems = (size_t)D_ * D_;        // 1048576
    // ws layout (bf16 elems):
    //   [Wo: 1M][Wq: 1M][Wk: 1M][Wv: 1M ... X region spans Wq..Wv+pad: 8M][Qw][Kw][Vw]
    //   (optionally) [Aqb][Akb][Avb] — bf16 copies of q,k,v for the pure-async GEMM.
    bf16* WoB = (bf16*)d_ws;            // elem 0
    bf16* WqB = WoB + welems;           // elem 1M
    bf16* WkB = WqB + welems;           // elem 2M
    bf16* WvB = WkB + welems;           // elem 3M
    bf16* Xb  = WqB;                    // elem 1M .. 1M+8M (aliases Wq/Wk/Wv by design)
    bf16* Qw  = WqB + elems;            // elem 1M+8M
    bf16* Kw  = Qw + elems;
    bf16* Vw  = Kw + elems;
    bf16* Aqb = Vw + elems;             // elem 33M (big-ws path only)
    bf16* Akb = Aqb + elems;
    bf16* Avb = Akb + elems;

    const size_t need_big = ((size_t)(Avb + elems) - (size_t)d_ws);  // 119.5 MB

    // 1. convert all four weight matrices (one launch)
    hipLaunchKernelGGL(cvtw, dim3(4 * (int)(welems / 4) / 256), dim3(256), 0, stream,
                       (const float4*)wq, (const float4*)wk, (const float4*)wv,
                       (const float4*)wo,
                       (bf16x4*)WqB, (bf16x4*)WkB, (bf16x4*)WvB, (bf16x4*)WoB);

    if (ws_size >= need_big) {
        // 2a. one-shot activation conversion, then pure-async bf16 QKV GEMM
        hipLaunchKernelGGL(cvtx, dim3((int)(elems / 8 / 256), 1, 3), dim3(256), 0, stream,
                           q, k, v, Aqb, Akb, Avb);
        hipLaunchKernelGGL(gemm_qkv_bf, dim3(D_ / 128, (B_ * S_) / 128, 3), dim3(256), 0,
                           stream, Aqb, Akb, Avb, WqB, WkB, WvB, Qw, Kw, Vw);
    } else {
        // 2b. fallback: fused in-register conversion path
        hipLaunchKernelGGL(gemm_qkv, dim3(D_ / 128, (B_ * S_) / 128, 3), dim3(256), 0,
                           stream, q, k, v, WqB, WkB, WvB, Qw, Kw, Vw);
    }

    // 3. attention
    hipLaunchKernelGGL(attn, dim3((S_ / 32) * B_ * H_), dim3(64), 0, stream, Qw, Kw, Vw, Xb);
    // 4. output projection -> d_out (f32)
    hipLaunchKernelGGL(gemm_out, dim3(D_ / 128, (B_ * S_) / 128), dim3(256), 0, stream,
                       Xb, WoB, (float*)d_out);
}

// Round 3
// 429.969 us; speedup vs baseline: 1.0392x; 1.0392x over previous
//
#include <hip/hip_runtime.h>
#include <hip/hip_bf16.h>
#include <stdint.h>

#define B_ 4
#define S_ 2048
#define D_ 1024
#define H_ 16
#define DK_ 64

typedef __hip_bfloat16 bf16;
typedef __attribute__((ext_vector_type(8))) __bf16 bf16x8;
typedef __attribute__((ext_vector_type(4))) __bf16 bf16x4;
typedef __attribute__((ext_vector_type(4))) float f32x4;
typedef __attribute__((ext_vector_type(4))) uint32_t u32x4;

// scale 1/sqrt(DK) folded with log2(e): Q pre-scaled so p = exp2(S^T) directly
#define QSCALE 0.18033688011112042f   // 0.125 * 1.4426950408889634

#if defined(__has_builtin)
#if __has_builtin(__builtin_amdgcn_exp2f)
#define EXP2(x) __builtin_amdgcn_exp2f(x)
#endif
#endif
#ifndef EXP2
#define EXP2(x) exp2f(x)
#endif

__device__ __forceinline__ void async_copy16(const void* g, void* l) {
    __builtin_amdgcn_global_load_lds((const __attribute__((address_space(1))) void*)g,
                                     (__attribute__((address_space(3))) void*)l,
                                     16, 0, 0);
}

__device__ __forceinline__ bf16x8 ld8(const bf16* p) {
    return *(const bf16x8*)p;
}

__device__ __forceinline__ uint32_t pk2(float a, float b) {
    union { __bf16 h; uint16_t u; } x, y;
    x.h = (__bf16)a; y.h = (__bf16)b;
    return (uint32_t)x.u | ((uint32_t)y.u << 16);
}

__device__ __forceinline__ bf16x8 cvt8(float4 u0, float4 u1) {
    return (bf16x8){(__bf16)u0.x, (__bf16)u0.y, (__bf16)u0.z, (__bf16)u0.w,
                    (__bf16)u1.x, (__bf16)u1.y, (__bf16)u1.z, (__bf16)u1.w};
}

// C-layout 16x32 P-tile (two 16x16 subtiles p0,p1) -> B-fragment of P^T (k=32, n=16)
__device__ __forceinline__ bf16x8 transpose_p(const float* p0, const float* p1,
                                              int srcl, bool loT) {
    uint32_t x0 = pk2(p0[0], p0[1]), x1 = pk2(p0[2], p0[3]);
    uint32_t y0 = pk2(p1[0], p1[1]), y1 = pk2(p1[2], p1[3]);
    u32x4 dw;
#pragma unroll
    for (int i = 0; i < 4; i++) {
        int sl = srcl + (i >> 1) * 16;
        uint32_t vA = (uint32_t)__shfl((int)((i & 1) ? x1 : x0), sl, 64);
        uint32_t vB = (uint32_t)__shfl((int)((i & 1) ? y1 : y0), sl, 64);
        dw[i] = loT ? vA : vB;
    }
    return __builtin_bit_cast(bf16x8, dw);
}

// convert the 4 weight matrices f32->bf16 in one launch (4 x 262144 float4)
__global__ __launch_bounds__(256) void cvtw(const float4* __restrict__ s0,
                                            const float4* __restrict__ s1,
                                            const float4* __restrict__ s2,
                                            const float4* __restrict__ s3,
                                            bf16x4* __restrict__ d0,
                                            bf16x4* __restrict__ d1,
                                            bf16x4* __restrict__ d2,
                                            bf16x4* __restrict__ d3) {
    int i = blockIdx.x * 256 + threadIdx.x;
    int seg = i >> 18;            // 262144 float4 per matrix
    int j   = i & 262143;
    const float4* s = seg == 0 ? s0 : seg == 1 ? s1 : seg == 2 ? s2 : s3;
    bf16x4*       d = seg == 0 ? d0 : seg == 1 ? d1 : seg == 2 ? d2 : d3;
    float4 f = s[j];
    d[j] = (bf16x4){(__bf16)f.x, (__bf16)f.y, (__bf16)f.z, (__bf16)f.w};
}

// one-shot activation conversion f32 -> bf16 (q,k,v), 8 elems / thread
__global__ __launch_bounds__(256) void cvtx(const float* __restrict__ s0,
                                            const float* __restrict__ s1,
                                            const float* __restrict__ s2,
                                            bf16* __restrict__ d0,
                                            bf16* __restrict__ d1,
                                            bf16* __restrict__ d2) {
    const int z = blockIdx.z;
    const float* s = z == 0 ? s0 : z == 1 ? s1 : s2;
    bf16*        d = z == 0 ? d0 : z == 1 ? d1 : d2;
    size_t i = ((size_t)blockIdx.x * 256 + threadIdx.x) * 8;
    float4 u0 = *(const float4*)(s + i);
    float4 u1 = *(const float4*)(s + i + 4);
    *(bf16x8*)(d + i) = cvt8(u0, u1);
}

// Pure-bf16 fused Q/K/V projection (m97 structure: dual global_load_lds staging).
// z=0: Q (scaled, layout [bh][s][dk]); z=1: K (same layout); z=2: V (transposed [bh][dk][s]).
__global__ __launch_bounds__(256) void gemm_qkv_bf(const bf16* __restrict__ Aq,
                                                   const bf16* __restrict__ Ak,
                                                   const bf16* __restrict__ Av,
                                                   const bf16* __restrict__ Wqb,
                                                   const bf16* __restrict__ Wkb,
                                                   const bf16* __restrict__ Wvb,
                                                   bf16* __restrict__ Oq,
                                                   bf16* __restrict__ Ok,
                                                   bf16* __restrict__ Ov) {
    __shared__ bf16 lA[128 * 32];
    __shared__ bf16 lW[128 * 32];
    const int z = blockIdx.z;
    const bf16* A = z == 0 ? Aq : z == 1 ? Ak : Av;
    const bf16* W = z == 0 ? Wqb : z == 1 ? Wkb : Wvb;
    bf16*      out = z == 0 ? Oq : z == 1 ? Ok : Ov;

    const int tid  = threadIdx.x;
    const int lane = tid & 63;
    const int quad = lane >> 4;
    const int lo   = lane & 15;
    const int wave = tid >> 6;
    const int wm   = (wave >> 1) * 64;
    const int wn   = (wave & 1) * 64;
    const int n0   = blockIdx.x * 128;
    const int m0   = blockIdx.y * 128;
    const int K    = 1024;

    f32x4 acc[4][4];
#pragma unroll
    for (int i = 0; i < 4; i++)
#pragma unroll
        for (int j = 0; j < 4; j++) acc[i][j] = (f32x4){0.f, 0.f, 0.f, 0.f};

    const int sr = tid >> 2;
    const int sc = (tid & 3) * 8;

    for (int k0 = 0; k0 < K; k0 += 32) {
        async_copy16(A + (size_t)(m0 + sr) * K + k0 + sc,       lA + sr * 32 + sc);
        async_copy16(A + (size_t)(m0 + 64 + sr) * K + k0 + sc,  lA + (64 + sr) * 32 + sc);
        async_copy16(W + (size_t)(n0 + sr) * K + k0 + sc,       lW + sr * 32 + sc);
        async_copy16(W + (size_t)(n0 + 64 + sr) * K + k0 + sc,  lW + (64 + sr) * 32 + sc);
        __syncthreads();

        bf16x8 af[4], bfr[4];
#pragma unroll
        for (int i = 0; i < 4; i++)
            af[i] = ld8(lA + (wm + i * 16 + lo) * 32 + quad * 8);
#pragma unroll
        for (int j = 0; j < 4; j++)
            bfr[j] = ld8(lW + (wn + j * 16 + lo) * 32 + quad * 8);
#pragma unroll
        for (int i = 0; i < 4; i++)
#pragma unroll
            for (int j = 0; j < 4; j++)
                acc[i][j] = __builtin_amdgcn_mfma_f32_16x16x32_bf16(af[i], bfr[j], acc[i][j], 0, 0, 0);
        __syncthreads();
    }

#pragma unroll
    for (int i = 0; i < 4; i++)
#pragma unroll
        for (int j = 0; j < 4; j++)
#pragma unroll
            for (int r = 0; r < 4; r++) {
                int m = m0 + wm + i * 16 + quad * 4 + r;
                int n = n0 + wn + j * 16 + lo;
                float val = acc[i][j][r];
                int b = m >> 11, s = m & (S_ - 1);
                int h = n >> 6, dk = n & 63;
                if (z == 0) {
                    out[((size_t)(b * H_ + h) * S_ + s) * DK_ + dk] =
                        __float2bfloat16(val * QSCALE);
                } else if (z == 1) {
                    out[((size_t)(b * H_ + h) * S_ + s) * DK_ + dk] = __float2bfloat16(val);
                } else {
                    out[((size_t)(b * H_ + h) * DK_ + dk) * S_ + s] = __float2bfloat16(val);
                }
            }
}

// Fallback (small workspace): fused in-register f32->bf16 conversion path.
__global__ __launch_bounds__(256) void gemm_qkv(const float* __restrict__ Aq,
                                                const float* __restrict__ Ak,
                                                const float* __restrict__ Av,
                                                const bf16* __restrict__ Wqb,
                                                const bf16* __restrict__ Wkb,
                                                const bf16* __restrict__ Wvb,
                                                bf16* __restrict__ Oq,
                                                bf16* __restrict__ Ok,
                                                bf16* __restrict__ Ov) {
    __shared__ bf16 lA[128 * 32];
    __shared__ bf16 lW[128 * 32];
    const int z = blockIdx.z;
    const float* A = z == 0 ? Aq : z == 1 ? Ak : Av;
    const bf16*  W = z == 0 ? Wqb : z == 1 ? Wkb : Wvb;
    bf16*      out = z == 0 ? Oq : z == 1 ? Ok : Ov;

    const int tid  = threadIdx.x;
    const int lane = tid & 63;
    const int quad = lane >> 4;
    const int lo   = lane & 15;
    const int wave = tid >> 6;
    const int wm   = (wave >> 1) * 64;
    const int wn   = (wave & 1) * 64;
    const int n0   = blockIdx.x * 128;
    const int m0   = blockIdx.y * 128;
    const int K    = 1024;

    f32x4 acc[4][4];
#pragma unroll
    for (int i = 0; i < 4; i++)
#pragma unroll
        for (int j = 0; j < 4; j++) acc[i][j] = (f32x4){0.f, 0.f, 0.f, 0.f};

    const int sr = tid >> 2;
    const int sc = (tid & 3) * 8;

    for (int k0 = 0; k0 < K; k0 += 32) {
        async_copy16(W + (size_t)(n0 + sr) * K + k0 + sc,       lW + sr * 32 + sc);
        async_copy16(W + (size_t)(n0 + 64 + sr) * K + k0 + sc,  lW + (64 + sr) * 32 + sc);
        const float* a0 = A + (size_t)(m0 + sr) * K + k0 + sc;
        const float* a1 = A + (size_t)(m0 + 64 + sr) * K + k0 + sc;
        float4 u0 = *(const float4*)a0;
        float4 u1 = *(const float4*)(a0 + 4);
        float4 u2 = *(const float4*)a1;
        float4 u3 = *(const float4*)(a1 + 4);
        *(bf16x8*)(lA + sr * 32 + sc)        = cvt8(u0, u1);
        *(bf16x8*)(lA + (64 + sr) * 32 + sc) = cvt8(u2, u3);
        __syncthreads();

        bf16x8 af[4], bfr[4];
#pragma unroll
        for (int i = 0; i < 4; i++)
            af[i] = ld8(lA + (wm + i * 16 + lo) * 32 + quad * 8);
#pragma unroll
        for (int j = 0; j < 4; j++)
            bfr[j] = ld8(lW + (wn + j * 16 + lo) * 32 + quad * 8);
#pragma unroll
        for (int i = 0; i < 4; i++)
#pragma unroll
            for (int j = 0; j < 4; j++)
                acc[i][j] = __builtin_amdgcn_mfma_f32_16x16x32_bf16(af[i], bfr[j], acc[i][j], 0, 0, 0);
        __syncthreads();
    }

#pragma unroll
    for (int i = 0; i < 4; i++)
#pragma unroll
        for (int j = 0; j < 4; j++)
#pragma unroll
            for (int r = 0; r < 4; r++) {
                int m = m0 + wm + i * 16 + quad * 4 + r;
                int n = n0 + wn + j * 16 + lo;
                float val = acc[i][j][r];
                int b = m >> 11, s = m & (S_ - 1);
                int h = n >> 6, dk = n & 63;
                if (z == 0) {
                    out[((size_t)(b * H_ + h) * S_ + s) * DK_ + dk] =
                        __float2bfloat16(val * QSCALE);
                } else if (z == 1) {
                    out[((size_t)(b * H_ + h) * S_ + s) * DK_ + dk] = __float2bfloat16(val);
                } else {
                    out[((size_t)(b * H_ + h) * DK_ + dk) * S_ + s] = __float2bfloat16(val);
                }
            }
}

// Final projection: A bf16 (attn output X), W bf16, out float32 [8192 x 1024]
__global__ __launch_bounds__(256) void gemm_out(const bf16* __restrict__ A,
                                                const bf16* __restrict__ W,
                                                float* __restrict__ out) {
    __shared__ bf16 lA[128 * 32];
    __shared__ bf16 lW[128 * 32];
    const int tid  = threadIdx.x;
    const int lane = tid & 63;
    const int quad = lane >> 4;
    const int lo   = lane & 15;
    const int wave = tid >> 6;
    const int wm   = (wave >> 1) * 64;
    const int wn   = (wave & 1) * 64;
    const int n0   = blockIdx.x * 128;
    const int m0   = blockIdx.y * 128;
    const int K    = 1024;

    f32x4 acc[4][4];
#pragma unroll
    for (int i = 0; i < 4; i++)
#pragma unroll
        for (int j = 0; j < 4; j++) acc[i][j] = (f32x4){0.f, 0.f, 0.f, 0.f};

    const int sr = tid >> 2;
    const int sc = (tid & 3) * 8;

    for (int k0 = 0; k0 < K; k0 += 32) {
        async_copy16(A + (size_t)(m0 + sr) * K + k0 + sc,       lA + sr * 32 + sc);
        async_copy16(A + (size_t)(m0 + 64 + sr) * K + k0 + sc,  lA + (64 + sr) * 32 + sc);
        async_copy16(W + (size_t)(n0 + sr) * K + k0 + sc,       lW + sr * 32 + sc);
        async_copy16(W + (size_t)(n0 + 64 + sr) * K + k0 + sc,  lW + (64 + sr) * 32 + sc);
        __syncthreads();

        bf16x8 af[4], bfr[4];
#pragma unroll
        for (int i = 0; i < 4; i++)
            af[i] = ld8(lA + (wm + i * 16 + lo) * 32 + quad * 8);
#pragma unroll
        for (int j = 0; j < 4; j++)
            bfr[j] = ld8(lW + (wn + j * 16 + lo) * 32 + quad * 8);
#pragma unroll
        for (int i = 0; i < 4; i++)
#pragma unroll
            for (int j = 0; j < 4; j++)
                acc[i][j] = __builtin_amdgcn_mfma_f32_16x16x32_bf16(af[i], bfr[j], acc[i][j], 0, 0, 0);
        __syncthreads();
    }

#pragma unroll
    for (int i = 0; i < 4; i++)
#pragma unroll
        for (int j = 0; j < 4; j++)
#pragma unroll
            for (int r = 0; r < 4; r++) {
                int m = m0 + wm + i * 16 + quad * 4 + r;
                int n = n0 + wn + j * 16 + lo;
                out[(size_t)m * D_ + n] = acc[i][j][r];
            }
}

// ---------------- attention helpers ----------------

__device__ __forceinline__ void loadK4(const bf16* __restrict__ Kp, int kv, int lo, int quad,
                                       bf16x8& k0, bf16x8& k1, bf16x8& k2, bf16x8& k3) {
    const bf16* kn = Kp + (size_t)(kv + lo) * DK_ + quad * 8;
    k0 = ld8(kn);
    k1 = ld8(kn + 32);
    k2 = ld8(kn + 16 * DK_);
    k3 = ld8(kn + 16 * DK_ + 32);
}

__device__ __forceinline__ void loadV4(const bf16* __restrict__ Vp, int kv, int lo, int quad,
                                       bf16x8& v0, bf16x8& v1, bf16x8& v2, bf16x8& v3) {
    const bf16* vn = Vp + (size_t)lo * S_ + kv + quad * 8;
    v0 = ld8(vn);
    v1 = ld8(vn + 16 * S_);
    v2 = ld8(vn + 32 * S_);
    v3 = ld8(vn + 48 * S_);
}

__device__ __forceinline__ void qk8(const bf16x8& k0, const bf16x8& k1,
                                    const bf16x8& k2, const bf16x8& k3,
                                    const bf16x8& bQa0, const bf16x8& bQa1,
                                    const bf16x8& bQb0, const bf16x8& bQb1,
                                    f32x4& s0, f32x4& s1, f32x4& s2, f32x4& s3) {
    s0 = (f32x4){0.f, 0.f, 0.f, 0.f};
    s1 = (f32x4){0.f, 0.f, 0.f, 0.f};
    s2 = (f32x4){0.f, 0.f, 0.f, 0.f};
    s3 = (f32x4){0.f, 0.f, 0.f, 0.f};
    s0 = __builtin_amdgcn_mfma_f32_16x16x32_bf16(k0, bQa0, s0, 0, 0, 0);
    s0 = __builtin_amdgcn_mfma_f32_16x16x32_bf16(k1, bQa1, s0, 0, 0, 0);
    s1 = __builtin_amdgcn_mfma_f32_16x16x32_bf16(k2, bQa0, s1, 0, 0, 0);
    s1 = __builtin_amdgcn_mfma_f32_16x16x32_bf16(k3, bQa1, s1, 0, 0, 0);
    s2 = __builtin_amdgcn_mfma_f32_16x16x32_bf16(k0, bQb0, s2, 0, 0, 0);
    s2 = __builtin_amdgcn_mfma_f32_16x16x32_bf16(k1, bQb1, s2, 0, 0, 0);
    s3 = __builtin_amdgcn_mfma_f32_16x16x32_bf16(k2, bQb0, s3, 0, 0, 0);
    s3 = __builtin_amdgcn_mfma_f32_16x16x32_bf16(k3, bQb1, s3, 0, 0, 0);
}

// softmax (exp2 + causal mask + kill) and P^T transpose for one 32-kv tile
__device__ __forceinline__ void sfx(bool masked, bool kill, int lo, int quad,
                                    int srcl, bool loT,
                                    const f32x4& s0, const f32x4& s1,
                                    const f32x4& s2, const f32x4& s3,
                                    float& lsumA, float& lsumB,
                                    bf16x8& bPA, bf16x8& bPB) {
    float pA0[4], pA1[4], pB0[4], pB1[4];
#pragma unroll
    for (int r = 0; r < 4; r++) {
        float eA0 = EXP2(s0[r]);
        float eA1 = EXP2(s1[r]);
        float eB0 = EXP2(s2[r]);
        float eB1 = EXP2(s3[r]);
        if (masked) {
            bool c = (quad * 4 + r) <= lo;
            eA0 = c ? eA0 : 0.f;
            eA1 = 0.f;
            eB1 = c ? eB1 : 0.f;
        }
        if (kill) { eA0 = 0.f; eA1 = 0.f; eB0 = 0.f; eB1 = 0.f; }
        pA0[r] = eA0; pA1[r] = eA1; pB0[r] = eB0; pB1[r] = eB1;
        lsumA += eA0 + eA1;
        lsumB += eB0 + eB1;
    }
    bPA = transpose_p(pA0, pA1, srcl, loT);
    bPB = transpose_p(pB0, pB1, srcl, loT);
}

// Transposed flash attention, causal, no-max softmax. 1 wave / 32 q rows.
// Two KV tiles per straight-line loop body: 16-MFMA QK cluster, two
// independent softmax chains (interleaved by the scheduler), 16-MFMA PV
// cluster. Odd-tile handled branchlessly via kill flag. setprio (T5)
// around both MFMA clusters.
__global__ __launch_bounds__(64, 4) void attn(const bf16* __restrict__ Q,
                                              const bf16* __restrict__ K,
                                              const bf16* __restrict__ Vt,
                                              bf16* __restrict__ X) {
    const int lane = threadIdx.x;
    const int quad = lane >> 4;
    const int lo   = lane & 15;
    const int idx  = blockIdx.x;
    const int bh   = idx & 63;          // XCD locality: one head stays on one XCD
    const int qb   = 63 - (idx >> 6);   // LPT: longest q-blocks dispatched first
    const int q0   = qb * 32;

    const bf16* Qp = Q  + (size_t)bh * S_ * DK_;
    const bf16* Kp = K  + (size_t)bh * S_ * DK_;
    const bf16* Vp = Vt + (size_t)bh * DK_ * S_;

    bf16x8 bQa0 = ld8(Qp + (size_t)(q0 + lo) * DK_ + quad * 8);
    bf16x8 bQa1 = ld8(Qp + (size_t)(q0 + lo) * DK_ + 32 + quad * 8);
    bf16x8 bQb0 = ld8(Qp + (size_t)(q0 + 16 + lo) * DK_ + quad * 8);
    bf16x8 bQb1 = ld8(Qp + (size_t)(q0 + 16 + lo) * DK_ + 32 + quad * 8);

    f32x4 outA[4], outB[4];
#pragma unroll
    for (int t = 0; t < 4; t++) {
        outA[t] = (f32x4){0.f, 0.f, 0.f, 0.f};
        outB[t] = (f32x4){0.f, 0.f, 0.f, 0.f};
    }
    float lsumA = 0.f, lsumB = 0.f;

    const int nfull = qb;
    const int NT    = nfull + 1;        // number of kv tiles (last one masked)
    const int srcl  = (quad & 1) * 32 + lo;
    const bool loT  = (quad < 2);

    for (int it = 0; it < NT; it += 2) {
        const bool has_o = (it + 1 < NT);
        const int kve = it * 32;
        const int kvo = has_o ? kve + 32 : kve;

        // K fragments for both tiles (die at end of QK cluster)
        bf16x8 kE0, kE1, kE2, kE3, kO0, kO1, kO2, kO3;
        loadK4(Kp, kve, lo, quad, kE0, kE1, kE2, kE3);
        loadK4(Kp, kvo, lo, quad, kO0, kO1, kO2, kO3);

        f32x4 sE0, sE1, sE2, sE3, sO0, sO1, sO2, sO3;
        __builtin_amdgcn_s_setprio(1);
        qk8(kE0, kE1, kE2, kE3, bQa0, bQa1, bQb0, bQb1, sE0, sE1, sE2, sE3);
        qk8(kO0, kO1, kO2, kO3, bQa0, bQa1, bQb0, bQb1, sO0, sO1, sO2, sO3);
        __builtin_amdgcn_s_setprio(0);

        // V fragments (issued early; latency covered by the softmax chains)
        bf16x8 aVe0, aVe1, aVe2, aVe3, aVo0, aVo1, aVo2, aVo3;
        loadV4(Vp, kve, lo, quad, aVe0, aVe1, aVe2, aVe3);
        loadV4(Vp, kvo, lo, quad, aVo0, aVo1, aVo2, aVo3);

        // two independent softmax+transpose chains
        bf16x8 bPAe, bPBe, bPAo, bPBo;
        sfx(it == nfull, false, lo, quad, srcl, loT,
            sE0, sE1, sE2, sE3, lsumA, lsumB, bPAe, bPBe);
        sfx(it + 1 == nfull, !has_o, lo, quad, srcl, loT,
            sO0, sO1, sO2, sO3, lsumA, lsumB, bPAo, bPBo);

        __builtin_amdgcn_s_setprio(1);
        outA[0] = __builtin_amdgcn_mfma_f32_16x16x32_bf16(aVe0, bPAe, outA[0], 0, 0, 0);
        outA[1] = __builtin_amdgcn_mfma_f32_16x16x32_bf16(aVe1, bPAe, outA[1], 0, 0, 0);
        outA[2] = __builtin_amdgcn_mfma_f32_16x16x32_bf16(aVe2, bPAe, outA[2], 0, 0, 0);
        outA[3] = __builtin_amdgcn_mfma_f32_16x16x32_bf16(aVe3, bPAe, outA[3], 0, 0, 0);
        outB[0] = __builtin_amdgcn_mfma_f32_16x16x32_bf16(aVe0, bPBe, outB[0], 0, 0, 0);
        outB[1] = __builtin_amdgcn_mfma_f32_16x16x32_bf16(aVe1, bPBe, outB[1], 0, 0, 0);
        outB[2] = __builtin_amdgcn_mfma_f32_16x16x32_bf16(aVe2, bPBe, outB[2], 0, 0, 0);
        outB[3] = __builtin_amdgcn_mfma_f32_16x16x32_bf16(aVe3, bPBe, outB[3], 0, 0, 0);
        outA[0] = __builtin_amdgcn_mfma_f32_16x16x32_bf16(aVo0, bPAo, outA[0], 0, 0, 0);
        outA[1] = __builtin_amdgcn_mfma_f32_16x16x32_bf16(aVo1, bPAo, outA[1], 0, 0, 0);
        outA[2] = __builtin_amdgcn_mfma_f32_16x16x32_bf16(aVo2, bPAo, outA[2], 0, 0, 0);
        outA[3] = __builtin_amdgcn_mfma_f32_16x16x32_bf16(aVo3, bPAo, outA[3], 0, 0, 0);
        outB[0] = __builtin_amdgcn_mfma_f32_16x16x32_bf16(aVo0, bPBo, outB[0], 0, 0, 0);
        outB[1] = __builtin_amdgcn_mfma_f32_16x16x32_bf16(aVo1, bPBo, outB[1], 0, 0, 0);
        outB[2] = __builtin_amdgcn_mfma_f32_16x16x32_bf16(aVo2, bPBo, outB[2], 0, 0, 0);
        outB[3] = __builtin_amdgcn_mfma_f32_16x16x32_bf16(aVo3, bPBo, outB[3], 0, 0, 0);
        __builtin_amdgcn_s_setprio(0);
    }

    lsumA += __shfl_xor(lsumA, 16, 64);
    lsumA += __shfl_xor(lsumA, 32, 64);
    lsumB += __shfl_xor(lsumB, 16, 64);
    lsumB += __shfl_xor(lsumB, 32, 64);
    const float rlA = 1.f / lsumA;
    const float rlB = 1.f / lsumB;

    const int b = bh >> 4, h = bh & 15;
    bf16* XpA = X + (size_t)(b * S_ + q0 + lo) * D_ + h * 64;
    bf16* XpB = XpA + (size_t)16 * D_;
#pragma unroll
    for (int t = 0; t < 4; t++) {
        uint32_t* dA = (uint32_t*)(XpA + t * 16 + quad * 4);
        dA[0] = pk2(outA[t][0] * rlA, outA[t][1] * rlA);
        dA[1] = pk2(outA[t][2] * rlA, outA[t][3] * rlA);
        uint32_t* dB = (uint32_t*)(XpB + t * 16 + quad * 4);
        dB[0] = pk2(outB[t][0] * rlB, outB[t][1] * rlB);
        dB[1] = pk2(outB[t][2] * rlB, outB[t][3] * rlB);
    }
}

extern "C" void kernel_launch(void* const* d_in, const int* in_sizes, int n_in,
                              void* d_out, int out_size, void* d_ws, size_t ws_size,
                              hipStream_t stream) {
    const float* q  = (const float*)d_in[0];
    const float* k  = (const float*)d_in[1];
    const float* v  = (const float*)d_in[2];
    const float* wq = (const float*)d_in[4];
    const float* wk = (const float*)d_in[5];
    const float* wv = (const float*)d_in[6];
    const float* wo = (const float*)d_in[7];

    const size_t elems  = (size_t)B_ * S_ * D_;   // 8388608
    const size_t welems = (size_t)D_ * D_;        // 1048576
    // ws layout (bf16 elems):
    //   [Wo: 1M][Wq: 1M][Wk: 1M][Wv: 1M ... X region spans Wq..Wv+pad: 8M][Qw][Kw][Vw]
    //   (optionally) [Aqb][Akb][Avb] — bf16 copies of q,k,v for the pure-async GEMM.
    bf16* WoB = (bf16*)d_ws;            // elem 0
    bf16* WqB = WoB + welems;           // elem 1M
    bf16* WkB = WqB + welems;           // elem 2M
    bf16* WvB = WkB + welems;           // elem 3M
    bf16* Xb  = WqB;                    // elem 1M .. 1M+8M (aliases Wq/Wk/Wv by design)
    bf16* Qw  = WqB + elems;            // elem 1M+8M
    bf16* Kw  = Qw + elems;
    bf16* Vw  = Kw + elems;
    bf16* Aqb = Vw + elems;             // elem 33M (big-ws path only)
    bf16* Akb = Aqb + elems;
    bf16* Avb = Akb + elems;

    const size_t need_big = ((size_t)(Avb + elems) - (size_t)d_ws);  // 119.5 MB

    // 1. convert all four weight matrices (one launch)
    hipLaunchKernelGGL(cvtw, dim3(4 * (int)(welems / 4) / 256), dim3(256), 0, stream,
                       (const float4*)wq, (const float4*)wk, (const float4*)wv,
                       (const float4*)wo,
                       (bf16x4*)WqB, (bf16x4*)WkB, (bf16x4*)WvB, (bf16x4*)WoB);

    if (ws_size >= need_big) {
        // 2a. one-shot activation conversion, then pure-async bf16 QKV GEMM
        hipLaunchKernelGGL(cvtx, dim3((int)(elems / 8 / 256), 1, 3), dim3(256), 0, stream,
                           q, k, v, Aqb, Akb, Avb);
        hipLaunchKernelGGL(gemm_qkv_bf, dim3(D_ / 128, (B_ * S_) / 128, 3), dim3(256), 0,
                           stream, Aqb, Akb, Avb, WqB, WkB, WvB, Qw, Kw, Vw);
    } else {
        // 2b. fallback: fused in-register conversion path
        hipLaunchKernelGGL(gemm_qkv, dim3(D_ / 128, (B_ * S_) / 128, 3), dim3(256), 0,
                           stream, q, k, v, WqB, WkB, WvB, Qw, Kw, Vw);
    }

    // 3. attention
    hipLaunchKernelGGL(attn, dim3((S_ / 32) * B_ * H_), dim3(64), 0, stream, Qw, Kw, Vw, Xb);
    // 4. output projection -> d_out (f32)
    hipLaunchKernelGGL(gemm_out, dim3(D_ / 128, (B_ * S_) / 128), dim3(256), 0, stream,
                       Xb, WoB, (float*)d_out);
}

// Round 4
// 372.827 us; speedup vs baseline: 1.1985x; 1.1533x over previous
//
#include <hip/hip_runtime.h>
#include <hip/hip_bf16.h>
#include <stdint.h>

#define B_ 4
#define S_ 2048
#define D_ 1024
#define H_ 16
#define DK_ 64

typedef __hip_bfloat16 bf16;
typedef __attribute__((ext_vector_type(8))) __bf16 bf16x8;
typedef __attribute__((ext_vector_type(4))) __bf16 bf16x4;
typedef __attribute__((ext_vector_type(4))) float f32x4;
typedef __attribute__((ext_vector_type(4))) uint32_t u32x4;

// scale 1/sqrt(DK) folded with log2(e): Q pre-scaled so p = exp2(S^T) directly
#define QSCALE 0.18033688011112042f   // 0.125 * 1.4426950408889634

#if defined(__has_builtin)
#if __has_builtin(__builtin_amdgcn_exp2f)
#define EXP2(x) __builtin_amdgcn_exp2f(x)
#endif
#endif
#ifndef EXP2
#define EXP2(x) exp2f(x)
#endif

__device__ __forceinline__ void async_copy16(const void* g, void* l) {
    __builtin_amdgcn_global_load_lds((const __attribute__((address_space(1))) void*)g,
                                     (__attribute__((address_space(3))) void*)l,
                                     16, 0, 0);
}

__device__ __forceinline__ bf16x8 ld8(const bf16* p) {
    return *(const bf16x8*)p;
}

__device__ __forceinline__ uint32_t pk2(float a, float b) {
    union { __bf16 h; uint16_t u; } x, y;
    x.h = (__bf16)a; y.h = (__bf16)b;
    return (uint32_t)x.u | ((uint32_t)y.u << 16);
}

__device__ __forceinline__ bf16x8 cvt8(float4 u0, float4 u1) {
    return (bf16x8){(__bf16)u0.x, (__bf16)u0.y, (__bf16)u0.z, (__bf16)u0.w,
                    (__bf16)u1.x, (__bf16)u1.y, (__bf16)u1.z, (__bf16)u1.w};
}

// C-layout 16x32 P-tile (two 16x16 subtiles p0,p1) -> B-fragment of P^T (k=32, n=16)
__device__ __forceinline__ bf16x8 transpose_p(const float* p0, const float* p1,
                                              int srcl, bool loT) {
    uint32_t x0 = pk2(p0[0], p0[1]), x1 = pk2(p0[2], p0[3]);
    uint32_t y0 = pk2(p1[0], p1[1]), y1 = pk2(p1[2], p1[3]);
    u32x4 dw;
#pragma unroll
    for (int i = 0; i < 4; i++) {
        int sl = srcl + (i >> 1) * 16;
        uint32_t vA = (uint32_t)__shfl((int)((i & 1) ? x1 : x0), sl, 64);
        uint32_t vB = (uint32_t)__shfl((int)((i & 1) ? y1 : y0), sl, 64);
        dw[i] = loT ? vA : vB;
    }
    return __builtin_bit_cast(bf16x8, dw);
}

// convert the 4 weight matrices f32->bf16 in one launch (4 x 262144 float4)
__global__ __launch_bounds__(256) void cvtw(const float4* __restrict__ s0,
                                            const float4* __restrict__ s1,
                                            const float4* __restrict__ s2,
                                            const float4* __restrict__ s3,
                                            bf16x4* __restrict__ d0,
                                            bf16x4* __restrict__ d1,
                                            bf16x4* __restrict__ d2,
                                            bf16x4* __restrict__ d3) {
    int i = blockIdx.x * 256 + threadIdx.x;
    int seg = i >> 18;            // 262144 float4 per matrix
    int j   = i & 262143;
    const float4* s = seg == 0 ? s0 : seg == 1 ? s1 : seg == 2 ? s2 : s3;
    bf16x4*       d = seg == 0 ? d0 : seg == 1 ? d1 : seg == 2 ? d2 : d3;
    float4 f = s[j];
    d[j] = (bf16x4){(__bf16)f.x, (__bf16)f.y, (__bf16)f.z, (__bf16)f.w};
}

// one-shot activation conversion f32 -> bf16 (q,k,v), 8 elems / thread
__global__ __launch_bounds__(256) void cvtx(const float* __restrict__ s0,
                                            const float* __restrict__ s1,
                                            const float* __restrict__ s2,
                                            bf16* __restrict__ d0,
                                            bf16* __restrict__ d1,
                                            bf16* __restrict__ d2) {
    const int z = blockIdx.z;
    const float* s = z == 0 ? s0 : z == 1 ? s1 : s2;
    bf16*        d = z == 0 ? d0 : z == 1 ? d1 : d2;
    size_t i = ((size_t)blockIdx.x * 256 + threadIdx.x) * 8;
    float4 u0 = *(const float4*)(s + i);
    float4 u1 = *(const float4*)(s + i + 4);
    *(bf16x8*)(d + i) = cvt8(u0, u1);
}

// Pure-bf16 fused Q/K/V projection (m97 structure: dual global_load_lds staging).
// z=0: Q (scaled, layout [bh][s][dk]); z=1: K (same layout); z=2: V (transposed [bh][dk][s]).
__global__ __launch_bounds__(256) void gemm_qkv_bf(const bf16* __restrict__ Aq,
                                                   const bf16* __restrict__ Ak,
                                                   const bf16* __restrict__ Av,
                                                   const bf16* __restrict__ Wqb,
                                                   const bf16* __restrict__ Wkb,
                                                   const bf16* __restrict__ Wvb,
                                                   bf16* __restrict__ Oq,
                                                   bf16* __restrict__ Ok,
                                                   bf16* __restrict__ Ov) {
    __shared__ bf16 lA[128 * 32];
    __shared__ bf16 lW[128 * 32];
    const int z = blockIdx.z;
    const bf16* A = z == 0 ? Aq : z == 1 ? Ak : Av;
    const bf16* W = z == 0 ? Wqb : z == 1 ? Wkb : Wvb;
    bf16*      out = z == 0 ? Oq : z == 1 ? Ok : Ov;

    const int tid  = threadIdx.x;
    const int lane = tid & 63;
    const int quad = lane >> 4;
    const int lo   = lane & 15;
    const int wave = tid >> 6;
    const int wm   = (wave >> 1) * 64;
    const int wn   = (wave & 1) * 64;
    const int n0   = blockIdx.x * 128;
    const int m0   = blockIdx.y * 128;
    const int K    = 1024;

    f32x4 acc[4][4];
#pragma unroll
    for (int i = 0; i < 4; i++)
#pragma unroll
        for (int j = 0; j < 4; j++) acc[i][j] = (f32x4){0.f, 0.f, 0.f, 0.f};

    const int sr = tid >> 2;
    const int sc = (tid & 3) * 8;

    for (int k0 = 0; k0 < K; k0 += 32) {
        async_copy16(A + (size_t)(m0 + sr) * K + k0 + sc,       lA + sr * 32 + sc);
        async_copy16(A + (size_t)(m0 + 64 + sr) * K + k0 + sc,  lA + (64 + sr) * 32 + sc);
        async_copy16(W + (size_t)(n0 + sr) * K + k0 + sc,       lW + sr * 32 + sc);
        async_copy16(W + (size_t)(n0 + 64 + sr) * K + k0 + sc,  lW + (64 + sr) * 32 + sc);
        __syncthreads();

        bf16x8 af[4], bfr[4];
#pragma unroll
        for (int i = 0; i < 4; i++)
            af[i] = ld8(lA + (wm + i * 16 + lo) * 32 + quad * 8);
#pragma unroll
        for (int j = 0; j < 4; j++)
            bfr[j] = ld8(lW + (wn + j * 16 + lo) * 32 + quad * 8);
#pragma unroll
        for (int i = 0; i < 4; i++)
#pragma unroll
            for (int j = 0; j < 4; j++)
                acc[i][j] = __builtin_amdgcn_mfma_f32_16x16x32_bf16(af[i], bfr[j], acc[i][j], 0, 0, 0);
        __syncthreads();
    }

#pragma unroll
    for (int i = 0; i < 4; i++)
#pragma unroll
        for (int j = 0; j < 4; j++)
#pragma unroll
            for (int r = 0; r < 4; r++) {
                int m = m0 + wm + i * 16 + quad * 4 + r;
                int n = n0 + wn + j * 16 + lo;
                float val = acc[i][j][r];
                int b = m >> 11, s = m & (S_ - 1);
                int h = n >> 6, dk = n & 63;
                if (z == 0) {
                    out[((size_t)(b * H_ + h) * S_ + s) * DK_ + dk] =
                        __float2bfloat16(val * QSCALE);
                } else if (z == 1) {
                    out[((size_t)(b * H_ + h) * S_ + s) * DK_ + dk] = __float2bfloat16(val);
                } else {
                    out[((size_t)(b * H_ + h) * DK_ + dk) * S_ + s] = __float2bfloat16(val);
                }
            }
}

// Fallback (small workspace): fused in-register f32->bf16 conversion path.
__global__ __launch_bounds__(256) void gemm_qkv(const float* __restrict__ Aq,
                                                const float* __restrict__ Ak,
                                                const float* __restrict__ Av,
                                                const bf16* __restrict__ Wqb,
                                                const bf16* __restrict__ Wkb,
                                                const bf16* __restrict__ Wvb,
                                                bf16* __restrict__ Oq,
                                                bf16* __restrict__ Ok,
                                                bf16* __restrict__ Ov) {
    __shared__ bf16 lA[128 * 32];
    __shared__ bf16 lW[128 * 32];
    const int z = blockIdx.z;
    const float* A = z == 0 ? Aq : z == 1 ? Ak : Av;
    const bf16*  W = z == 0 ? Wqb : z == 1 ? Wkb : Wvb;
    bf16*      out = z == 0 ? Oq : z == 1 ? Ok : Ov;

    const int tid  = threadIdx.x;
    const int lane = tid & 63;
    const int quad = lane >> 4;
    const int lo   = lane & 15;
    const int wave = tid >> 6;
    const int wm   = (wave >> 1) * 64;
    const int wn   = (wave & 1) * 64;
    const int n0   = blockIdx.x * 128;
    const int m0   = blockIdx.y * 128;
    const int K    = 1024;

    f32x4 acc[4][4];
#pragma unroll
    for (int i = 0; i < 4; i++)
#pragma unroll
        for (int j = 0; j < 4; j++) acc[i][j] = (f32x4){0.f, 0.f, 0.f, 0.f};

    const int sr = tid >> 2;
    const int sc = (tid & 3) * 8;

    for (int k0 = 0; k0 < K; k0 += 32) {
        async_copy16(W + (size_t)(n0 + sr) * K + k0 + sc,       lW + sr * 32 + sc);
        async_copy16(W + (size_t)(n0 + 64 + sr) * K + k0 + sc,  lW + (64 + sr) * 32 + sc);
        const float* a0 = A + (size_t)(m0 + sr) * K + k0 + sc;
        const float* a1 = A + (size_t)(m0 + 64 + sr) * K + k0 + sc;
        float4 u0 = *(const float4*)a0;
        float4 u1 = *(const float4*)(a0 + 4);
        float4 u2 = *(const float4*)a1;
        float4 u3 = *(const float4*)(a1 + 4);
        *(bf16x8*)(lA + sr * 32 + sc)        = cvt8(u0, u1);
        *(bf16x8*)(lA + (64 + sr) * 32 + sc) = cvt8(u2, u3);
        __syncthreads();

        bf16x8 af[4], bfr[4];
#pragma unroll
        for (int i = 0; i < 4; i++)
            af[i] = ld8(lA + (wm + i * 16 + lo) * 32 + quad * 8);
#pragma unroll
        for (int j = 0; j < 4; j++)
            bfr[j] = ld8(lW + (wn + j * 16 + lo) * 32 + quad * 8);
#pragma unroll
        for (int i = 0; i < 4; i++)
#pragma unroll
            for (int j = 0; j < 4; j++)
                acc[i][j] = __builtin_amdgcn_mfma_f32_16x16x32_bf16(af[i], bfr[j], acc[i][j], 0, 0, 0);
        __syncthreads();
    }

#pragma unroll
    for (int i = 0; i < 4; i++)
#pragma unroll
        for (int j = 0; j < 4; j++)
#pragma unroll
            for (int r = 0; r < 4; r++) {
                int m = m0 + wm + i * 16 + quad * 4 + r;
                int n = n0 + wn + j * 16 + lo;
                float val = acc[i][j][r];
                int b = m >> 11, s = m & (S_ - 1);
                int h = n >> 6, dk = n & 63;
                if (z == 0) {
                    out[((size_t)(b * H_ + h) * S_ + s) * DK_ + dk] =
                        __float2bfloat16(val * QSCALE);
                } else if (z == 1) {
                    out[((size_t)(b * H_ + h) * S_ + s) * DK_ + dk] = __float2bfloat16(val);
                } else {
                    out[((size_t)(b * H_ + h) * DK_ + dk) * S_ + s] = __float2bfloat16(val);
                }
            }
}

// Final projection: A bf16 (attn output X), W bf16, out float32 [8192 x 1024]
__global__ __launch_bounds__(256) void gemm_out(const bf16* __restrict__ A,
                                                const bf16* __restrict__ W,
                                                float* __restrict__ out) {
    __shared__ bf16 lA[128 * 32];
    __shared__ bf16 lW[128 * 32];
    const int tid  = threadIdx.x;
    const int lane = tid & 63;
    const int quad = lane >> 4;
    const int lo   = lane & 15;
    const int wave = tid >> 6;
    const int wm   = (wave >> 1) * 64;
    const int wn   = (wave & 1) * 64;
    const int n0   = blockIdx.x * 128;
    const int m0   = blockIdx.y * 128;
    const int K    = 1024;

    f32x4 acc[4][4];
#pragma unroll
    for (int i = 0; i < 4; i++)
#pragma unroll
        for (int j = 0; j < 4; j++) acc[i][j] = (f32x4){0.f, 0.f, 0.f, 0.f};

    const int sr = tid >> 2;
    const int sc = (tid & 3) * 8;

    for (int k0 = 0; k0 < K; k0 += 32) {
        async_copy16(A + (size_t)(m0 + sr) * K + k0 + sc,       lA + sr * 32 + sc);
        async_copy16(A + (size_t)(m0 + 64 + sr) * K + k0 + sc,  lA + (64 + sr) * 32 + sc);
        async_copy16(W + (size_t)(n0 + sr) * K + k0 + sc,       lW + sr * 32 + sc);
        async_copy16(W + (size_t)(n0 + 64 + sr) * K + k0 + sc,  lW + (64 + sr) * 32 + sc);
        __syncthreads();

        bf16x8 af[4], bfr[4];
#pragma unroll
        for (int i = 0; i < 4; i++)
            af[i] = ld8(lA + (wm + i * 16 + lo) * 32 + quad * 8);
#pragma unroll
        for (int j = 0; j < 4; j++)
            bfr[j] = ld8(lW + (wn + j * 16 + lo) * 32 + quad * 8);
#pragma unroll
        for (int i = 0; i < 4; i++)
#pragma unroll
            for (int j = 0; j < 4; j++)
                acc[i][j] = __builtin_amdgcn_mfma_f32_16x16x32_bf16(af[i], bfr[j], acc[i][j], 0, 0, 0);
        __syncthreads();
    }

#pragma unroll
    for (int i = 0; i < 4; i++)
#pragma unroll
        for (int j = 0; j < 4; j++)
#pragma unroll
            for (int r = 0; r < 4; r++) {
                int m = m0 + wm + i * 16 + quad * 4 + r;
                int n = n0 + wn + j * 16 + lo;
                out[(size_t)m * D_ + n] = acc[i][j][r];
            }
}

// ---------------- attention ----------------
// Transposed flash attention, causal, no-max softmax. 1 wave / 64 q rows.
// 4 Q-subtiles share each K/V tile: 32 MFMA per 8 global loads (2x the
// arithmetic intensity of the 32-row version), 4 independent softmax
// chains per tile for intra-wave ILP. No cross-iteration register
// pipelining (r1/r2 spill lesson).
__global__ __launch_bounds__(64) void attn(const bf16* __restrict__ Q,
                                           const bf16* __restrict__ K,
                                           const bf16* __restrict__ Vt,
                                           bf16* __restrict__ X) {
    const int lane = threadIdx.x;
    const int quad = lane >> 4;
    const int lo   = lane & 15;
    const int idx  = blockIdx.x;
    const int bh   = idx & 63;          // XCD locality: one head stays on one XCD
    const int qbp  = 31 - (idx >> 6);   // LPT: longest q-blocks dispatched first
    const int q0   = qbp * 64;

    const bf16* Qp = Q  + (size_t)bh * S_ * DK_;
    const bf16* Kp = K  + (size_t)bh * S_ * DK_;
    const bf16* Vp = Vt + (size_t)bh * DK_ * S_;

    // 4 Q-subtiles of 16 rows each: rows q0 + qs*16 + lo
    bf16x8 bQ[4][2];
#pragma unroll
    for (int qs = 0; qs < 4; qs++) {
        const bf16* qp = Qp + (size_t)(q0 + qs * 16 + lo) * DK_ + quad * 8;
        bQ[qs][0] = ld8(qp);
        bQ[qs][1] = ld8(qp + 32);
    }

    f32x4 out[4][4];      // [q-subtile][dk-frag]
    float lsum[4] = {0.f, 0.f, 0.f, 0.f};
#pragma unroll
    for (int qs = 0; qs < 4; qs++)
#pragma unroll
        for (int t = 0; t < 4; t++) out[qs][t] = (f32x4){0.f, 0.f, 0.f, 0.f};

    const int NT   = 2 * qbp + 2;       // kv tiles: 2*qbp full-ish + 2 diagonal
    const int srcl = (quad & 1) * 32 + lo;
    const bool loT = (quad < 2);

    bf16x8 aK0, aK1, aK2, aK3;
    {
        const bf16* kn = Kp + (size_t)lo * DK_ + quad * 8;
        aK0 = ld8(kn); aK1 = ld8(kn + 32);
        aK2 = ld8(kn + 16 * DK_); aK3 = ld8(kn + 16 * DK_ + 32);
    }

    for (int it = 0; it < NT; ++it) {
        const int kv0 = it * 32;
        // mode per 32-row pair: 0=full, 1=diagonal, 2=killed
        const int am = (it < 2 * qbp) ? 0 : (it == 2 * qbp ? 1 : 2);
        const int bm = (it < 2 * qbp + 1) ? 0 : 1;

        bf16x8 aV[4];
#pragma unroll
        for (int t = 0; t < 4; t++)
            aV[t] = ld8(Vp + (size_t)(t * 16 + lo) * S_ + kv0 + quad * 8);

        // QK^T: 16 MFMA, K frags shared across 4 Q-subtiles
        f32x4 st[4][2];
        __builtin_amdgcn_s_setprio(1);
#pragma unroll
        for (int qs = 0; qs < 4; qs++) {
            f32x4 t0 = (f32x4){0.f, 0.f, 0.f, 0.f};
            f32x4 t1 = (f32x4){0.f, 0.f, 0.f, 0.f};
            t0 = __builtin_amdgcn_mfma_f32_16x16x32_bf16(aK0, bQ[qs][0], t0, 0, 0, 0);
            t0 = __builtin_amdgcn_mfma_f32_16x16x32_bf16(aK1, bQ[qs][1], t0, 0, 0, 0);
            t1 = __builtin_amdgcn_mfma_f32_16x16x32_bf16(aK2, bQ[qs][0], t1, 0, 0, 0);
            t1 = __builtin_amdgcn_mfma_f32_16x16x32_bf16(aK3, bQ[qs][1], t1, 0, 0, 0);
            st[qs][0] = t0; st[qs][1] = t1;
        }
        __builtin_amdgcn_s_setprio(0);

        // prefetch next K tile (overwrites aK after last use above)
        {
            int kvn = it + 1; if (kvn >= NT) kvn = NT - 1;
            const bf16* kn = Kp + (size_t)(kvn * 32 + lo) * DK_ + quad * 8;
            aK0 = ld8(kn); aK1 = ld8(kn + 32);
            aK2 = ld8(kn + 16 * DK_); aK3 = ld8(kn + 16 * DK_ + 32);
        }

        // softmax + transpose per 32-row pair (two independent chains each)
        bf16x8 bP[4];
#pragma unroll
        for (int pr = 0; pr < 2; pr++) {
            const int mode = pr == 0 ? am : bm;
            const int sl = pr * 2, sh = pr * 2 + 1;
            float pl0[4], pl1[4], ph0[4], ph1[4];
#pragma unroll
            for (int r = 0; r < 4; r++) {
                float el0 = EXP2(st[sl][0][r]);
                float el1 = EXP2(st[sl][1][r]);
                float eh0 = EXP2(st[sh][0][r]);
                float eh1 = EXP2(st[sh][1][r]);
                if (mode == 1) {
                    bool c = (quad * 4 + r) <= lo;
                    el0 = c ? el0 : 0.f;
                    el1 = 0.f;
                    eh1 = c ? eh1 : 0.f;
                } else if (mode == 2) {
                    el0 = 0.f; el1 = 0.f; eh0 = 0.f; eh1 = 0.f;
                }
                pl0[r] = el0; pl1[r] = el1; ph0[r] = eh0; ph1[r] = eh1;
                lsum[sl] += el0 + el1;
                lsum[sh] += eh0 + eh1;
            }
            bP[sl] = transpose_p(pl0, pl1, srcl, loT);
            bP[sh] = transpose_p(ph0, ph1, srcl, loT);
        }

        // PV: 16 MFMA, V frags shared across 4 P fragments
        __builtin_amdgcn_s_setprio(1);
#pragma unroll
        for (int qs = 0; qs < 4; qs++)
#pragma unroll
            for (int t = 0; t < 4; t++)
                out[qs][t] = __builtin_amdgcn_mfma_f32_16x16x32_bf16(aV[t], bP[qs], out[qs][t], 0, 0, 0);
        __builtin_amdgcn_s_setprio(0);
    }

    const int b = bh >> 4, h = bh & 15;
#pragma unroll
    for (int qs = 0; qs < 4; qs++) {
        float ls = lsum[qs];
        ls += __shfl_xor(ls, 16, 64);
        ls += __shfl_xor(ls, 32, 64);
        const float rl = 1.f / ls;
        bf16* Xp = X + (size_t)(b * S_ + q0 + qs * 16 + lo) * D_ + h * 64;
#pragma unroll
        for (int t = 0; t < 4; t++) {
            uint32_t* d = (uint32_t*)(Xp + t * 16 + quad * 4);
            d[0] = pk2(out[qs][t][0] * rl, out[qs][t][1] * rl);
            d[1] = pk2(out[qs][t][2] * rl, out[qs][t][3] * rl);
        }
    }
}

extern "C" void kernel_launch(void* const* d_in, const int* in_sizes, int n_in,
                              void* d_out, int out_size, void* d_ws, size_t ws_size,
                              hipStream_t stream) {
    const float* q  = (const float*)d_in[0];
    const float* k  = (const float*)d_in[1];
    const float* v  = (const float*)d_in[2];
    const float* wq = (const float*)d_in[4];
    const float* wk = (const float*)d_in[5];
    const float* wv = (const float*)d_in[6];
    const float* wo = (const float*)d_in[7];

    const size_t elems  = (size_t)B_ * S_ * D_;   // 8388608
    const size_t welems = (size_t)D_ * D_;        // 1048576
    // ws layout (bf16 elems):
    //   [Wo: 1M][Wq: 1M][Wk: 1M][Wv: 1M ... X region spans Wq..Wv+pad: 8M][Qw][Kw][Vw]
    //   (optionally) [Aqb][Akb][Avb] — bf16 copies of q,k,v for the pure-async GEMM.
    bf16* WoB = (bf16*)d_ws;            // elem 0
    bf16* WqB = WoB + welems;           // elem 1M
    bf16* WkB = WqB + welems;           // elem 2M
    bf16* WvB = WkB + welems;           // elem 3M
    bf16* Xb  = WqB;                    // elem 1M .. 1M+8M (aliases Wq/Wk/Wv by design)
    bf16* Qw  = WqB + elems;            // elem 1M+8M
    bf16* Kw  = Qw + elems;
    bf16* Vw  = Kw + elems;
    bf16* Aqb = Vw + elems;             // elem 33M (big-ws path only)
    bf16* Akb = Aqb + elems;
    bf16* Avb = Akb + elems;

    const size_t need_big = ((size_t)(Avb + elems) - (size_t)d_ws);  // 119.5 MB

    // 1. convert all four weight matrices (one launch)
    hipLaunchKernelGGL(cvtw, dim3(4 * (int)(welems / 4) / 256), dim3(256), 0, stream,
                       (const float4*)wq, (const float4*)wk, (const float4*)wv,
                       (const float4*)wo,
                       (bf16x4*)WqB, (bf16x4*)WkB, (bf16x4*)WvB, (bf16x4*)WoB);

    if (ws_size >= need_big) {
        // 2a. one-shot activation conversion, then pure-async bf16 QKV GEMM
        hipLaunchKernelGGL(cvtx, dim3((int)(elems / 8 / 256), 1, 3), dim3(256), 0, stream,
                           q, k, v, Aqb, Akb, Avb);
        hipLaunchKernelGGL(gemm_qkv_bf, dim3(D_ / 128, (B_ * S_) / 128, 3), dim3(256), 0,
                           stream, Aqb, Akb, Avb, WqB, WkB, WvB, Qw, Kw, Vw);
    } else {
        // 2b. fallback: fused in-register conversion path
        hipLaunchKernelGGL(gemm_qkv, dim3(D_ / 128, (B_ * S_) / 128, 3), dim3(256), 0,
                           stream, q, k, v, WqB, WkB, WvB, Qw, Kw, Vw);
    }

    // 3. attention: 1 wave per 64 q rows
    hipLaunchKernelGGL(attn, dim3((S_ / 64) * B_ * H_), dim3(64), 0, stream, Qw, Kw, Vw, Xb);
    // 4. output projection -> d_out (f32)
    hipLaunchKernelGGL(gemm_out, dim3(D_ / 128, (B_ * S_) / 128), dim3(256), 0, stream,
                       Xb, WoB, (float*)d_out);
}

// Round 5
// 358.275 us; speedup vs baseline: 1.2472x; 1.0406x over previous
//
#include <hip/hip_runtime.h>
#include <hip/hip_bf16.h>
#include <stdint.h>

#define B_ 4
#define S_ 2048
#define D_ 1024
#define H_ 16
#define DK_ 64

typedef __hip_bfloat16 bf16;
typedef __attribute__((ext_vector_type(8))) __bf16 bf16x8;
typedef __attribute__((ext_vector_type(4))) __bf16 bf16x4;
typedef __attribute__((ext_vector_type(4))) float f32x4;
typedef __attribute__((ext_vector_type(4))) uint32_t u32x4;

// scale 1/sqrt(DK) folded with log2(e): Q pre-scaled so p = exp2(S^T) directly
#define QSCALE 0.18033688011112042f   // 0.125 * 1.4426950408889634

#if defined(__has_builtin)
#if __has_builtin(__builtin_amdgcn_exp2f)
#define EXP2(x) __builtin_amdgcn_exp2f(x)
#endif
#endif
#ifndef EXP2
#define EXP2(x) exp2f(x)
#endif

__device__ __forceinline__ void async_copy16(const void* g, void* l) {
    __builtin_amdgcn_global_load_lds((const __attribute__((address_space(1))) void*)g,
                                     (__attribute__((address_space(3))) void*)l,
                                     16, 0, 0);
}

__device__ __forceinline__ bf16x8 ld8(const bf16* p) {
    return *(const bf16x8*)p;
}

__device__ __forceinline__ uint32_t pk2(float a, float b) {
    union { __bf16 h; uint16_t u; } x, y;
    x.h = (__bf16)a; y.h = (__bf16)b;
    return (uint32_t)x.u | ((uint32_t)y.u << 16);
}

__device__ __forceinline__ bf16x8 cvt8(float4 u0, float4 u1) {
    return (bf16x8){(__bf16)u0.x, (__bf16)u0.y, (__bf16)u0.z, (__bf16)u0.w,
                    (__bf16)u1.x, (__bf16)u1.y, (__bf16)u1.z, (__bf16)u1.w};
}

// C-layout 16x32 P-tile (two 16x16 subtiles p0,p1) -> B-fragment of P^T (k=32, n=16)
__device__ __forceinline__ bf16x8 transpose_p(const float* p0, const float* p1,
                                              int srcl, bool loT) {
    uint32_t x0 = pk2(p0[0], p0[1]), x1 = pk2(p0[2], p0[3]);
    uint32_t y0 = pk2(p1[0], p1[1]), y1 = pk2(p1[2], p1[3]);
    u32x4 dw;
#pragma unroll
    for (int i = 0; i < 4; i++) {
        int sl = srcl + (i >> 1) * 16;
        uint32_t vA = (uint32_t)__shfl((int)((i & 1) ? x1 : x0), sl, 64);
        uint32_t vB = (uint32_t)__shfl((int)((i & 1) ? y1 : y0), sl, 64);
        dw[i] = loT ? vA : vB;
    }
    return __builtin_bit_cast(bf16x8, dw);
}

// convert the 4 weight matrices f32->bf16 in one launch (4 x 262144 float4)
__global__ __launch_bounds__(256) void cvtw(const float4* __restrict__ s0,
                                            const float4* __restrict__ s1,
                                            const float4* __restrict__ s2,
                                            const float4* __restrict__ s3,
                                            bf16x4* __restrict__ d0,
                                            bf16x4* __restrict__ d1,
                                            bf16x4* __restrict__ d2,
                                            bf16x4* __restrict__ d3) {
    int i = blockIdx.x * 256 + threadIdx.x;
    int seg = i >> 18;            // 262144 float4 per matrix
    int j   = i & 262143;
    const float4* s = seg == 0 ? s0 : seg == 1 ? s1 : seg == 2 ? s2 : s3;
    bf16x4*       d = seg == 0 ? d0 : seg == 1 ? d1 : seg == 2 ? d2 : d3;
    float4 f = s[j];
    d[j] = (bf16x4){(__bf16)f.x, (__bf16)f.y, (__bf16)f.z, (__bf16)f.w};
}

// one-shot activation conversion f32 -> bf16 (q,k,v), 8 elems / thread
__global__ __launch_bounds__(256) void cvtx(const float* __restrict__ s0,
                                            const float* __restrict__ s1,
                                            const float* __restrict__ s2,
                                            bf16* __restrict__ d0,
                                            bf16* __restrict__ d1,
                                            bf16* __restrict__ d2) {
    const int z = blockIdx.z;
    const float* s = z == 0 ? s0 : z == 1 ? s1 : s2;
    bf16*        d = z == 0 ? d0 : z == 1 ? d1 : d2;
    size_t i = ((size_t)blockIdx.x * 256 + threadIdx.x) * 8;
    float4 u0 = *(const float4*)(s + i);
    float4 u1 = *(const float4*)(s + i + 4);
    *(bf16x8*)(d + i) = cvt8(u0, u1);
}

// Pure-bf16 fused Q/K/V projection (m97 structure: dual global_load_lds staging).
// z=0: Q (scaled, layout [bh][s][dk]); z=1: K (same layout); z=2: V (transposed [bh][dk][s]).
__global__ __launch_bounds__(256) void gemm_qkv_bf(const bf16* __restrict__ Aq,
                                                   const bf16* __restrict__ Ak,
                                                   const bf16* __restrict__ Av,
                                                   const bf16* __restrict__ Wqb,
                                                   const bf16* __restrict__ Wkb,
                                                   const bf16* __restrict__ Wvb,
                                                   bf16* __restrict__ Oq,
                                                   bf16* __restrict__ Ok,
                                                   bf16* __restrict__ Ov) {
    __shared__ bf16 lA[128 * 32];
    __shared__ bf16 lW[128 * 32];
    const int z = blockIdx.z;
    const bf16* A = z == 0 ? Aq : z == 1 ? Ak : Av;
    const bf16* W = z == 0 ? Wqb : z == 1 ? Wkb : Wvb;
    bf16*      out = z == 0 ? Oq : z == 1 ? Ok : Ov;

    const int tid  = threadIdx.x;
    const int lane = tid & 63;
    const int quad = lane >> 4;
    const int lo   = lane & 15;
    const int wave = tid >> 6;
    const int wm   = (wave >> 1) * 64;
    const int wn   = (wave & 1) * 64;
    const int n0   = blockIdx.x * 128;
    const int m0   = blockIdx.y * 128;
    const int K    = 1024;

    f32x4 acc[4][4];
#pragma unroll
    for (int i = 0; i < 4; i++)
#pragma unroll
        for (int j = 0; j < 4; j++) acc[i][j] = (f32x4){0.f, 0.f, 0.f, 0.f};

    const int sr = tid >> 2;
    const int sc = (tid & 3) * 8;

    for (int k0 = 0; k0 < K; k0 += 32) {
        async_copy16(A + (size_t)(m0 + sr) * K + k0 + sc,       lA + sr * 32 + sc);
        async_copy16(A + (size_t)(m0 + 64 + sr) * K + k0 + sc,  lA + (64 + sr) * 32 + sc);
        async_copy16(W + (size_t)(n0 + sr) * K + k0 + sc,       lW + sr * 32 + sc);
        async_copy16(W + (size_t)(n0 + 64 + sr) * K + k0 + sc,  lW + (64 + sr) * 32 + sc);
        __syncthreads();

        bf16x8 af[4], bfr[4];
#pragma unroll
        for (int i = 0; i < 4; i++)
            af[i] = ld8(lA + (wm + i * 16 + lo) * 32 + quad * 8);
#pragma unroll
        for (int j = 0; j < 4; j++)
            bfr[j] = ld8(lW + (wn + j * 16 + lo) * 32 + quad * 8);
#pragma unroll
        for (int i = 0; i < 4; i++)
#pragma unroll
            for (int j = 0; j < 4; j++)
                acc[i][j] = __builtin_amdgcn_mfma_f32_16x16x32_bf16(af[i], bfr[j], acc[i][j], 0, 0, 0);
        __syncthreads();
    }

#pragma unroll
    for (int i = 0; i < 4; i++)
#pragma unroll
        for (int j = 0; j < 4; j++)
#pragma unroll
            for (int r = 0; r < 4; r++) {
                int m = m0 + wm + i * 16 + quad * 4 + r;
                int n = n0 + wn + j * 16 + lo;
                float val = acc[i][j][r];
                int b = m >> 11, s = m & (S_ - 1);
                int h = n >> 6, dk = n & 63;
                if (z == 0) {
                    out[((size_t)(b * H_ + h) * S_ + s) * DK_ + dk] =
                        __float2bfloat16(val * QSCALE);
                } else if (z == 1) {
                    out[((size_t)(b * H_ + h) * S_ + s) * DK_ + dk] = __float2bfloat16(val);
                } else {
                    out[((size_t)(b * H_ + h) * DK_ + dk) * S_ + s] = __float2bfloat16(val);
                }
            }
}

// Fallback (small workspace): fused in-register f32->bf16 conversion path.
__global__ __launch_bounds__(256) void gemm_qkv(const float* __restrict__ Aq,
                                                const float* __restrict__ Ak,
                                                const float* __restrict__ Av,
                                                const bf16* __restrict__ Wqb,
                                                const bf16* __restrict__ Wkb,
                                                const bf16* __restrict__ Wvb,
                                                bf16* __restrict__ Oq,
                                                bf16* __restrict__ Ok,
                                                bf16* __restrict__ Ov) {
    __shared__ bf16 lA[128 * 32];
    __shared__ bf16 lW[128 * 32];
    const int z = blockIdx.z;
    const float* A = z == 0 ? Aq : z == 1 ? Ak : Av;
    const bf16*  W = z == 0 ? Wqb : z == 1 ? Wkb : Wvb;
    bf16*      out = z == 0 ? Oq : z == 1 ? Ok : Ov;

    const int tid  = threadIdx.x;
    const int lane = tid & 63;
    const int quad = lane >> 4;
    const int lo   = lane & 15;
    const int wave = tid >> 6;
    const int wm   = (wave >> 1) * 64;
    const int wn   = (wave & 1) * 64;
    const int n0   = blockIdx.x * 128;
    const int m0   = blockIdx.y * 128;
    const int K    = 1024;

    f32x4 acc[4][4];
#pragma unroll
    for (int i = 0; i < 4; i++)
#pragma unroll
        for (int j = 0; j < 4; j++) acc[i][j] = (f32x4){0.f, 0.f, 0.f, 0.f};

    const int sr = tid >> 2;
    const int sc = (tid & 3) * 8;

    for (int k0 = 0; k0 < K; k0 += 32) {
        async_copy16(W + (size_t)(n0 + sr) * K + k0 + sc,       lW + sr * 32 + sc);
        async_copy16(W + (size_t)(n0 + 64 + sr) * K + k0 + sc,  lW + (64 + sr) * 32 + sc);
        const float* a0 = A + (size_t)(m0 + sr) * K + k0 + sc;
        const float* a1 = A + (size_t)(m0 + 64 + sr) * K + k0 + sc;
        float4 u0 = *(const float4*)a0;
        float4 u1 = *(const float4*)(a0 + 4);
        float4 u2 = *(const float4*)a1;
        float4 u3 = *(const float4*)(a1 + 4);
        *(bf16x8*)(lA + sr * 32 + sc)        = cvt8(u0, u1);
        *(bf16x8*)(lA + (64 + sr) * 32 + sc) = cvt8(u2, u3);
        __syncthreads();

        bf16x8 af[4], bfr[4];
#pragma unroll
        for (int i = 0; i < 4; i++)
            af[i] = ld8(lA + (wm + i * 16 + lo) * 32 + quad * 8);
#pragma unroll
        for (int j = 0; j < 4; j++)
            bfr[j] = ld8(lW + (wn + j * 16 + lo) * 32 + quad * 8);
#pragma unroll
        for (int i = 0; i < 4; i++)
#pragma unroll
            for (int j = 0; j < 4; j++)
                acc[i][j] = __builtin_amdgcn_mfma_f32_16x16x32_bf16(af[i], bfr[j], acc[i][j], 0, 0, 0);
        __syncthreads();
    }

#pragma unroll
    for (int i = 0; i < 4; i++)
#pragma unroll
        for (int j = 0; j < 4; j++)
#pragma unroll
            for (int r = 0; r < 4; r++) {
                int m = m0 + wm + i * 16 + quad * 4 + r;
                int n = n0 + wn + j * 16 + lo;
                float val = acc[i][j][r];
                int b = m >> 11, s = m & (S_ - 1);
                int h = n >> 6, dk = n & 63;
                if (z == 0) {
                    out[((size_t)(b * H_ + h) * S_ + s) * DK_ + dk] =
                        __float2bfloat16(val * QSCALE);
                } else if (z == 1) {
                    out[((size_t)(b * H_ + h) * S_ + s) * DK_ + dk] = __float2bfloat16(val);
                } else {
                    out[((size_t)(b * H_ + h) * DK_ + dk) * S_ + s] = __float2bfloat16(val);
                }
            }
}

// Final projection: A bf16 (attn output X), W bf16, out float32 [8192 x 1024]
__global__ __launch_bounds__(256) void gemm_out(const bf16* __restrict__ A,
                                                const bf16* __restrict__ W,
                                                float* __restrict__ out) {
    __shared__ bf16 lA[128 * 32];
    __shared__ bf16 lW[128 * 32];
    const int tid  = threadIdx.x;
    const int lane = tid & 63;
    const int quad = lane >> 4;
    const int lo   = lane & 15;
    const int wave = tid >> 6;
    const int wm   = (wave >> 1) * 64;
    const int wn   = (wave & 1) * 64;
    const int n0   = blockIdx.x * 128;
    const int m0   = blockIdx.y * 128;
    const int K    = 1024;

    f32x4 acc[4][4];
#pragma unroll
    for (int i = 0; i < 4; i++)
#pragma unroll
        for (int j = 0; j < 4; j++) acc[i][j] = (f32x4){0.f, 0.f, 0.f, 0.f};

    const int sr = tid >> 2;
    const int sc = (tid & 3) * 8;

    for (int k0 = 0; k0 < K; k0 += 32) {
        async_copy16(A + (size_t)(m0 + sr) * K + k0 + sc,       lA + sr * 32 + sc);
        async_copy16(A + (size_t)(m0 + 64 + sr) * K + k0 + sc,  lA + (64 + sr) * 32 + sc);
        async_copy16(W + (size_t)(n0 + sr) * K + k0 + sc,       lW + sr * 32 + sc);
        async_copy16(W + (size_t)(n0 + 64 + sr) * K + k0 + sc,  lW + (64 + sr) * 32 + sc);
        __syncthreads();

        bf16x8 af[4], bfr[4];
#pragma unroll
        for (int i = 0; i < 4; i++)
            af[i] = ld8(lA + (wm + i * 16 + lo) * 32 + quad * 8);
#pragma unroll
        for (int j = 0; j < 4; j++)
            bfr[j] = ld8(lW + (wn + j * 16 + lo) * 32 + quad * 8);
#pragma unroll
        for (int i = 0; i < 4; i++)
#pragma unroll
            for (int j = 0; j < 4; j++)
                acc[i][j] = __builtin_amdgcn_mfma_f32_16x16x32_bf16(af[i], bfr[j], acc[i][j], 0, 0, 0);
        __syncthreads();
    }

#pragma unroll
    for (int i = 0; i < 4; i++)
#pragma unroll
        for (int j = 0; j < 4; j++)
#pragma unroll
            for (int r = 0; r < 4; r++) {
                int m = m0 + wm + i * 16 + quad * 4 + r;
                int n = n0 + wn + j * 16 + lo;
                out[(size_t)m * D_ + n] = acc[i][j][r];
            }
}

// ---------------- attention ----------------
// Transposed flash attention, causal, no-max softmax.
// 128-thread blocks: 2 waves KV-split one 64-row q-chunk (flash-decoding
// style). No-max softmax => partials merge by pure addition (O=O0+O1,
// l=l0+l1) through LDS — no rescale, no extra global traffic.
// Per wave: 4 Q-subtiles share each K/V tile (32 MFMA / 8 loads).
__global__ __launch_bounds__(128) void attn(const bf16* __restrict__ Q,
                                            const bf16* __restrict__ K,
                                            const bf16* __restrict__ Vt,
                                            bf16* __restrict__ X) {
    __shared__ f32x4 sO[4][4][64];   // 16 KB: wave1 partial output
    __shared__ float sL[4][64];      // 1 KB: wave1 partial lsum (per-lane)
    const int tid  = threadIdx.x;
    const int wid  = tid >> 6;
    const int lane = tid & 63;
    const int quad = lane >> 4;
    const int lo   = lane & 15;
    const int idx  = blockIdx.x;
    const int bh   = idx & 63;          // XCD locality: one head stays on one XCD
    const int qbp  = 31 - (idx >> 6);   // LPT: longest q-blocks dispatched first
    const int q0   = qbp * 64;

    const bf16* Qp = Q  + (size_t)bh * S_ * DK_;
    const bf16* Kp = K  + (size_t)bh * S_ * DK_;
    const bf16* Vp = Vt + (size_t)bh * DK_ * S_;

    // 4 Q-subtiles of 16 rows each: rows q0 + qs*16 + lo
    bf16x8 bQ[4][2];
#pragma unroll
    for (int qs = 0; qs < 4; qs++) {
        const bf16* qp = Qp + (size_t)(q0 + qs * 16 + lo) * DK_ + quad * 8;
        bQ[qs][0] = ld8(qp);
        bQ[qs][1] = ld8(qp + 32);
    }

    f32x4 out[4][4];      // [q-subtile][dk-frag]
    float lsum[4] = {0.f, 0.f, 0.f, 0.f};
#pragma unroll
    for (int qs = 0; qs < 4; qs++)
#pragma unroll
        for (int t = 0; t < 4; t++) out[qs][t] = (f32x4){0.f, 0.f, 0.f, 0.f};

    const int NT   = 2 * qbp + 2;       // kv tiles (even); last two diagonal-ish
    const int half = NT >> 1;
    const int it0  = wid * half;        // wave0: [0,half), wave1: [half,NT)
    const int it1  = it0 + half;
    const int srcl = (quad & 1) * 32 + lo;
    const bool loT = (quad < 2);

    bf16x8 aK0, aK1, aK2, aK3;
    {
        const bf16* kn = Kp + (size_t)(it0 * 32 + lo) * DK_ + quad * 8;
        aK0 = ld8(kn); aK1 = ld8(kn + 32);
        aK2 = ld8(kn + 16 * DK_); aK3 = ld8(kn + 16 * DK_ + 32);
    }

    for (int it = it0; it < it1; ++it) {
        const int kv0 = it * 32;
        // mode per 32-row pair: 0=full, 1=diagonal, 2=killed
        const int am = (it < 2 * qbp) ? 0 : (it == 2 * qbp ? 1 : 2);
        const int bm = (it < 2 * qbp + 1) ? 0 : 1;

        bf16x8 aV[4];
#pragma unroll
        for (int t = 0; t < 4; t++)
            aV[t] = ld8(Vp + (size_t)(t * 16 + lo) * S_ + kv0 + quad * 8);

        // QK^T: 16 MFMA, K frags shared across 4 Q-subtiles
        f32x4 st[4][2];
        __builtin_amdgcn_s_setprio(1);
#pragma unroll
        for (int qs = 0; qs < 4; qs++) {
            f32x4 t0 = (f32x4){0.f, 0.f, 0.f, 0.f};
            f32x4 t1 = (f32x4){0.f, 0.f, 0.f, 0.f};
            t0 = __builtin_amdgcn_mfma_f32_16x16x32_bf16(aK0, bQ[qs][0], t0, 0, 0, 0);
            t0 = __builtin_amdgcn_mfma_f32_16x16x32_bf16(aK1, bQ[qs][1], t0, 0, 0, 0);
            t1 = __builtin_amdgcn_mfma_f32_16x16x32_bf16(aK2, bQ[qs][0], t1, 0, 0, 0);
            t1 = __builtin_amdgcn_mfma_f32_16x16x32_bf16(aK3, bQ[qs][1], t1, 0, 0, 0);
            st[qs][0] = t0; st[qs][1] = t1;
        }
        __builtin_amdgcn_s_setprio(0);

        // prefetch next K tile (overwrites aK after last use above)
        {
            int kvn = it + 1; if (kvn >= it1) kvn = it1 - 1;
            const bf16* kn = Kp + (size_t)(kvn * 32 + lo) * DK_ + quad * 8;
            aK0 = ld8(kn); aK1 = ld8(kn + 32);
            aK2 = ld8(kn + 16 * DK_); aK3 = ld8(kn + 16 * DK_ + 32);
        }

        // softmax + transpose per 32-row pair (two independent chains each)
        bf16x8 bP[4];
#pragma unroll
        for (int pr = 0; pr < 2; pr++) {
            const int mode = pr == 0 ? am : bm;
            const int sl = pr * 2, sh = pr * 2 + 1;
            float pl0[4], pl1[4], ph0[4], ph1[4];
#pragma unroll
            for (int r = 0; r < 4; r++) {
                float el0 = EXP2(st[sl][0][r]);
                float el1 = EXP2(st[sl][1][r]);
                float eh0 = EXP2(st[sh][0][r]);
                float eh1 = EXP2(st[sh][1][r]);
                if (mode == 1) {
                    bool c = (quad * 4 + r) <= lo;
                    el0 = c ? el0 : 0.f;
                    el1 = 0.f;
                    eh1 = c ? eh1 : 0.f;
                } else if (mode == 2) {
                    el0 = 0.f; el1 = 0.f; eh0 = 0.f; eh1 = 0.f;
                }
                pl0[r] = el0; pl1[r] = el1; ph0[r] = eh0; ph1[r] = eh1;
                lsum[sl] += el0 + el1;
                lsum[sh] += eh0 + eh1;
            }
            bP[sl] = transpose_p(pl0, pl1, srcl, loT);
            bP[sh] = transpose_p(ph0, ph1, srcl, loT);
        }

        // PV: 16 MFMA, V frags shared across 4 P fragments
        __builtin_amdgcn_s_setprio(1);
#pragma unroll
        for (int qs = 0; qs < 4; qs++)
#pragma unroll
            for (int t = 0; t < 4; t++)
                out[qs][t] = __builtin_amdgcn_mfma_f32_16x16x32_bf16(aV[t], bP[qs], out[qs][t], 0, 0, 0);
        __builtin_amdgcn_s_setprio(0);
    }

    // merge wave1's partials into wave0 through LDS (pure add: no-max softmax)
    if (wid == 1) {
#pragma unroll
        for (int qs = 0; qs < 4; qs++) {
#pragma unroll
            for (int t = 0; t < 4; t++) sO[qs][t][lane] = out[qs][t];
            sL[qs][lane] = lsum[qs];
        }
    }
    __syncthreads();
    if (wid == 0) {
        const int b = bh >> 4, h = bh & 15;
#pragma unroll
        for (int qs = 0; qs < 4; qs++) {
#pragma unroll
            for (int t = 0; t < 4; t++) {
                f32x4 p = sO[qs][t][lane];
                out[qs][t][0] += p[0]; out[qs][t][1] += p[1];
                out[qs][t][2] += p[2]; out[qs][t][3] += p[3];
            }
            float ls = lsum[qs] + sL[qs][lane];
            ls += __shfl_xor(ls, 16, 64);
            ls += __shfl_xor(ls, 32, 64);
            const float rl = 1.f / ls;
            bf16* Xp = X + (size_t)(b * S_ + q0 + qs * 16 + lo) * D_ + h * 64;
#pragma unroll
            for (int t = 0; t < 4; t++) {
                uint32_t* d = (uint32_t*)(Xp + t * 16 + quad * 4);
                d[0] = pk2(out[qs][t][0] * rl, out[qs][t][1] * rl);
                d[1] = pk2(out[qs][t][2] * rl, out[qs][t][3] * rl);
            }
        }
    }
}

extern "C" void kernel_launch(void* const* d_in, const int* in_sizes, int n_in,
                              void* d_out, int out_size, void* d_ws, size_t ws_size,
                              hipStream_t stream) {
    const float* q  = (const float*)d_in[0];
    const float* k  = (const float*)d_in[1];
    const float* v  = (const float*)d_in[2];
    const float* wq = (const float*)d_in[4];
    const float* wk = (const float*)d_in[5];
    const float* wv = (const float*)d_in[6];
    const float* wo = (const float*)d_in[7];

    const size_t elems  = (size_t)B_ * S_ * D_;   // 8388608
    const size_t welems = (size_t)D_ * D_;        // 1048576
    // ws layout (bf16 elems):
    //   [Wo: 1M][Wq: 1M][Wk: 1M][Wv: 1M ... X region spans Wq..Wv+pad: 8M][Qw][Kw][Vw]
    //   (optionally) [Aqb][Akb][Avb] — bf16 copies of q,k,v for the pure-async GEMM.
    bf16* WoB = (bf16*)d_ws;            // elem 0
    bf16* WqB = WoB + welems;           // elem 1M
    bf16* WkB = WqB + welems;           // elem 2M
    bf16* WvB = WkB + welems;           // elem 3M
    bf16* Xb  = WqB;                    // elem 1M .. 1M+8M (aliases Wq/Wk/Wv by design)
    bf16* Qw  = WqB + elems;            // elem 1M+8M
    bf16* Kw  = Qw + elems;
    bf16* Vw  = Kw + elems;
    bf16* Aqb = Vw + elems;             // elem 33M (big-ws path only)
    bf16* Akb = Aqb + elems;
    bf16* Avb = Akb + elems;

    const size_t need_big = ((size_t)(Avb + elems) - (size_t)d_ws);  // 119.5 MB

    // 1. convert all four weight matrices (one launch)
    hipLaunchKernelGGL(cvtw, dim3(4 * (int)(welems / 4) / 256), dim3(256), 0, stream,
                       (const float4*)wq, (const float4*)wk, (const float4*)wv,
                       (const float4*)wo,
                       (bf16x4*)WqB, (bf16x4*)WkB, (bf16x4*)WvB, (bf16x4*)WoB);

    if (ws_size >= need_big) {
        // 2a. one-shot activation conversion, then pure-async bf16 QKV GEMM
        hipLaunchKernelGGL(cvtx, dim3((int)(elems / 8 / 256), 1, 3), dim3(256), 0, stream,
                           q, k, v, Aqb, Akb, Avb);
        hipLaunchKernelGGL(gemm_qkv_bf, dim3(D_ / 128, (B_ * S_) / 128, 3), dim3(256), 0,
                           stream, Aqb, Akb, Avb, WqB, WkB, WvB, Qw, Kw, Vw);
    } else {
        // 2b. fallback: fused in-register conversion path
        hipLaunchKernelGGL(gemm_qkv, dim3(D_ / 128, (B_ * S_) / 128, 3), dim3(256), 0,
                           stream, q, k, v, WqB, WkB, WvB, Qw, Kw, Vw);
    }

    // 3. attention: 128-thread blocks, 2 waves KV-split per 64-row q-chunk
    hipLaunchKernelGGL(attn, dim3((S_ / 64) * B_ * H_), dim3(128), 0, stream, Qw, Kw, Vw, Xb);
    // 4. output projection -> d_out (f32)
    hipLaunchKernelGGL(gemm_out, dim3(D_ / 128, (B_ * S_) / 128), dim3(256), 0, stream,
                       Xb, WoB, (float*)d_out);
}

// Round 6
// 344.768 us; speedup vs baseline: 1.2961x; 1.0392x over previous
//
#include <hip/hip_runtime.h>
#include <hip/hip_bf16.h>
#include <stdint.h>

#define B_ 4
#define S_ 2048
#define D_ 1024
#define H_ 16
#define DK_ 64

typedef __hip_bfloat16 bf16;
typedef __attribute__((ext_vector_type(8))) __bf16 bf16x8;
typedef __attribute__((ext_vector_type(4))) __bf16 bf16x4;
typedef __attribute__((ext_vector_type(4))) float f32x4;
typedef __attribute__((ext_vector_type(4))) uint32_t u32x4;

// scale 1/sqrt(DK) folded with log2(e): Q pre-scaled so p = exp2(S^T) directly
#define QSCALE 0.18033688011112042f   // 0.125 * 1.4426950408889634

#if defined(__has_builtin)
#if __has_builtin(__builtin_amdgcn_exp2f)
#define EXP2(x) __builtin_amdgcn_exp2f(x)
#endif
#endif
#ifndef EXP2
#define EXP2(x) exp2f(x)
#endif

__device__ __forceinline__ void async_copy16(const void* g, void* l) {
    __builtin_amdgcn_global_load_lds((const __attribute__((address_space(1))) void*)g,
                                     (__attribute__((address_space(3))) void*)l,
                                     16, 0, 0);
}

__device__ __forceinline__ bf16x8 ld8(const bf16* p) {
    return *(const bf16x8*)p;
}

__device__ __forceinline__ uint32_t pk2(float a, float b) {
    union { __bf16 h; uint16_t u; } x, y;
    x.h = (__bf16)a; y.h = (__bf16)b;
    return (uint32_t)x.u | ((uint32_t)y.u << 16);
}

__device__ __forceinline__ bf16x8 cvt8(float4 u0, float4 u1) {
    return (bf16x8){(__bf16)u0.x, (__bf16)u0.y, (__bf16)u0.z, (__bf16)u0.w,
                    (__bf16)u1.x, (__bf16)u1.y, (__bf16)u1.z, (__bf16)u1.w};
}

// C-layout 16x32 P-tile (two 16x16 subtiles p0,p1) -> B-fragment of P^T (k=32, n=16)
__device__ __forceinline__ bf16x8 transpose_p(const float* p0, const float* p1,
                                              int srcl, bool loT) {
    uint32_t x0 = pk2(p0[0], p0[1]), x1 = pk2(p0[2], p0[3]);
    uint32_t y0 = pk2(p1[0], p1[1]), y1 = pk2(p1[2], p1[3]);
    u32x4 dw;
#pragma unroll
    for (int i = 0; i < 4; i++) {
        int sl = srcl + (i >> 1) * 16;
        uint32_t vA = (uint32_t)__shfl((int)((i & 1) ? x1 : x0), sl, 64);
        uint32_t vB = (uint32_t)__shfl((int)((i & 1) ? y1 : y0), sl, 64);
        dw[i] = loT ? vA : vB;
    }
    return __builtin_bit_cast(bf16x8, dw);
}

// convert the 4 weight matrices f32->bf16 in one launch (4 x 262144 float4)
__global__ __launch_bounds__(256) void cvtw(const float4* __restrict__ s0,
                                            const float4* __restrict__ s1,
                                            const float4* __restrict__ s2,
                                            const float4* __restrict__ s3,
                                            bf16x4* __restrict__ d0,
                                            bf16x4* __restrict__ d1,
                                            bf16x4* __restrict__ d2,
                                            bf16x4* __restrict__ d3) {
    int i = blockIdx.x * 256 + threadIdx.x;
    int seg = i >> 18;            // 262144 float4 per matrix
    int j   = i & 262143;
    const float4* s = seg == 0 ? s0 : seg == 1 ? s1 : seg == 2 ? s2 : s3;
    bf16x4*       d = seg == 0 ? d0 : seg == 1 ? d1 : seg == 2 ? d2 : d3;
    float4 f = s[j];
    d[j] = (bf16x4){(__bf16)f.x, (__bf16)f.y, (__bf16)f.z, (__bf16)f.w};
}

// one-shot activation conversion f32 -> bf16 (q,k,v), 8 elems / thread
__global__ __launch_bounds__(256) void cvtx(const float* __restrict__ s0,
                                            const float* __restrict__ s1,
                                            const float* __restrict__ s2,
                                            bf16* __restrict__ d0,
                                            bf16* __restrict__ d1,
                                            bf16* __restrict__ d2) {
    const int z = blockIdx.z;
    const float* s = z == 0 ? s0 : z == 1 ? s1 : s2;
    bf16*        d = z == 0 ? d0 : z == 1 ? d1 : d2;
    size_t i = ((size_t)blockIdx.x * 256 + threadIdx.x) * 8;
    float4 u0 = *(const float4*)(s + i);
    float4 u1 = *(const float4*)(s + i + 4);
    *(bf16x8*)(d + i) = cvt8(u0, u1);
}

// Pure-bf16 fused Q/K/V projection (m97 structure: dual global_load_lds staging).
// Grid is (m=64, n=8, z=3): XCD = wgid%8 = m-tile%8, so each A m-panel is
// fetched by exactly ONE XCD's L2 (A is the big operand); W re-reads are
// L2-resident + L3-shared. (T1 swizzle, correctly oriented.)
// z=0: Q (scaled, layout [bh][s][dk]); z=1: K (same layout); z=2: V (transposed [bh][dk][s]).
__global__ __launch_bounds__(256) void gemm_qkv_bf(const bf16* __restrict__ Aq,
                                                   const bf16* __restrict__ Ak,
                                                   const bf16* __restrict__ Av,
                                                   const bf16* __restrict__ Wqb,
                                                   const bf16* __restrict__ Wkb,
                                                   const bf16* __restrict__ Wvb,
                                                   bf16* __restrict__ Oq,
                                                   bf16* __restrict__ Ok,
                                                   bf16* __restrict__ Ov) {
    __shared__ bf16 lA[128 * 32];
    __shared__ bf16 lW[128 * 32];
    const int z = blockIdx.z;
    const bf16* A = z == 0 ? Aq : z == 1 ? Ak : Av;
    const bf16* W = z == 0 ? Wqb : z == 1 ? Wkb : Wvb;
    bf16*      out = z == 0 ? Oq : z == 1 ? Ok : Ov;

    const int tid  = threadIdx.x;
    const int lane = tid & 63;
    const int quad = lane >> 4;
    const int lo   = lane & 15;
    const int wave = tid >> 6;
    const int wm   = (wave >> 1) * 64;
    const int wn   = (wave & 1) * 64;
    const int n0   = blockIdx.y * 128;   // swapped: y = n-tile (8)
    const int m0   = blockIdx.x * 128;   // swapped: x = m-tile (64) -> XCD key
    const int K    = 1024;

    f32x4 acc[4][4];
#pragma unroll
    for (int i = 0; i < 4; i++)
#pragma unroll
        for (int j = 0; j < 4; j++) acc[i][j] = (f32x4){0.f, 0.f, 0.f, 0.f};

    const int sr = tid >> 2;
    const int sc = (tid & 3) * 8;

    for (int k0 = 0; k0 < K; k0 += 32) {
        async_copy16(A + (size_t)(m0 + sr) * K + k0 + sc,       lA + sr * 32 + sc);
        async_copy16(A + (size_t)(m0 + 64 + sr) * K + k0 + sc,  lA + (64 + sr) * 32 + sc);
        async_copy16(W + (size_t)(n0 + sr) * K + k0 + sc,       lW + sr * 32 + sc);
        async_copy16(W + (size_t)(n0 + 64 + sr) * K + k0 + sc,  lW + (64 + sr) * 32 + sc);
        __syncthreads();

        bf16x8 af[4], bfr[4];
#pragma unroll
        for (int i = 0; i < 4; i++)
            af[i] = ld8(lA + (wm + i * 16 + lo) * 32 + quad * 8);
#pragma unroll
        for (int j = 0; j < 4; j++)
            bfr[j] = ld8(lW + (wn + j * 16 + lo) * 32 + quad * 8);
#pragma unroll
        for (int i = 0; i < 4; i++)
#pragma unroll
            for (int j = 0; j < 4; j++)
                acc[i][j] = __builtin_amdgcn_mfma_f32_16x16x32_bf16(af[i], bfr[j], acc[i][j], 0, 0, 0);
        __syncthreads();
    }

#pragma unroll
    for (int i = 0; i < 4; i++)
#pragma unroll
        for (int j = 0; j < 4; j++)
#pragma unroll
            for (int r = 0; r < 4; r++) {
                int m = m0 + wm + i * 16 + quad * 4 + r;
                int n = n0 + wn + j * 16 + lo;
                float val = acc[i][j][r];
                int b = m >> 11, s = m & (S_ - 1);
                int h = n >> 6, dk = n & 63;
                if (z == 0) {
                    out[((size_t)(b * H_ + h) * S_ + s) * DK_ + dk] =
                        __float2bfloat16(val * QSCALE);
                } else if (z == 1) {
                    out[((size_t)(b * H_ + h) * S_ + s) * DK_ + dk] = __float2bfloat16(val);
                } else {
                    out[((size_t)(b * H_ + h) * DK_ + dk) * S_ + s] = __float2bfloat16(val);
                }
            }
}

// Fallback (small workspace): fused in-register f32->bf16 conversion path.
__global__ __launch_bounds__(256) void gemm_qkv(const float* __restrict__ Aq,
                                                const float* __restrict__ Ak,
                                                const float* __restrict__ Av,
                                                const bf16* __restrict__ Wqb,
                                                const bf16* __restrict__ Wkb,
                                                const bf16* __restrict__ Wvb,
                                                bf16* __restrict__ Oq,
                                                bf16* __restrict__ Ok,
                                                bf16* __restrict__ Ov) {
    __shared__ bf16 lA[128 * 32];
    __shared__ bf16 lW[128 * 32];
    const int z = blockIdx.z;
    const float* A = z == 0 ? Aq : z == 1 ? Ak : Av;
    const bf16*  W = z == 0 ? Wqb : z == 1 ? Wkb : Wvb;
    bf16*      out = z == 0 ? Oq : z == 1 ? Ok : Ov;

    const int tid  = threadIdx.x;
    const int lane = tid & 63;
    const int quad = lane >> 4;
    const int lo   = lane & 15;
    const int wave = tid >> 6;
    const int wm   = (wave >> 1) * 64;
    const int wn   = (wave & 1) * 64;
    const int n0   = blockIdx.y * 128;
    const int m0   = blockIdx.x * 128;
    const int K    = 1024;

    f32x4 acc[4][4];
#pragma unroll
    for (int i = 0; i < 4; i++)
#pragma unroll
        for (int j = 0; j < 4; j++) acc[i][j] = (f32x4){0.f, 0.f, 0.f, 0.f};

    const int sr = tid >> 2;
    const int sc = (tid & 3) * 8;

    for (int k0 = 0; k0 < K; k0 += 32) {
        async_copy16(W + (size_t)(n0 + sr) * K + k0 + sc,       lW + sr * 32 + sc);
        async_copy16(W + (size_t)(n0 + 64 + sr) * K + k0 + sc,  lW + (64 + sr) * 32 + sc);
        const float* a0 = A + (size_t)(m0 + sr) * K + k0 + sc;
        const float* a1 = A + (size_t)(m0 + 64 + sr) * K + k0 + sc;
        float4 u0 = *(const float4*)a0;
        float4 u1 = *(const float4*)(a0 + 4);
        float4 u2 = *(const float4*)a1;
        float4 u3 = *(const float4*)(a1 + 4);
        *(bf16x8*)(lA + sr * 32 + sc)        = cvt8(u0, u1);
        *(bf16x8*)(lA + (64 + sr) * 32 + sc) = cvt8(u2, u3);
        __syncthreads();

        bf16x8 af[4], bfr[4];
#pragma unroll
        for (int i = 0; i < 4; i++)
            af[i] = ld8(lA + (wm + i * 16 + lo) * 32 + quad * 8);
#pragma unroll
        for (int j = 0; j < 4; j++)
            bfr[j] = ld8(lW + (wn + j * 16 + lo) * 32 + quad * 8);
#pragma unroll
        for (int i = 0; i < 4; i++)
#pragma unroll
            for (int j = 0; j < 4; j++)
                acc[i][j] = __builtin_amdgcn_mfma_f32_16x16x32_bf16(af[i], bfr[j], acc[i][j], 0, 0, 0);
        __syncthreads();
    }

#pragma unroll
    for (int i = 0; i < 4; i++)
#pragma unroll
        for (int j = 0; j < 4; j++)
#pragma unroll
            for (int r = 0; r < 4; r++) {
                int m = m0 + wm + i * 16 + quad * 4 + r;
                int n = n0 + wn + j * 16 + lo;
                float val = acc[i][j][r];
                int b = m >> 11, s = m & (S_ - 1);
                int h = n >> 6, dk = n & 63;
                if (z == 0) {
                    out[((size_t)(b * H_ + h) * S_ + s) * DK_ + dk] =
                        __float2bfloat16(val * QSCALE);
                } else if (z == 1) {
                    out[((size_t)(b * H_ + h) * S_ + s) * DK_ + dk] = __float2bfloat16(val);
                } else {
                    out[((size_t)(b * H_ + h) * DK_ + dk) * S_ + s] = __float2bfloat16(val);
                }
            }
}

// Final projection: A bf16 (attn output X), W bf16, out float32 [8192 x 1024]
// Grid (m=64, n=8): same XCD orientation as gemm_qkv_bf.
__global__ __launch_bounds__(256) void gemm_out(const bf16* __restrict__ A,
                                                const bf16* __restrict__ W,
                                                float* __restrict__ out) {
    __shared__ bf16 lA[128 * 32];
    __shared__ bf16 lW[128 * 32];
    const int tid  = threadIdx.x;
    const int lane = tid & 63;
    const int quad = lane >> 4;
    const int lo   = lane & 15;
    const int wave = tid >> 6;
    const int wm   = (wave >> 1) * 64;
    const int wn   = (wave & 1) * 64;
    const int n0   = blockIdx.y * 128;
    const int m0   = blockIdx.x * 128;
    const int K    = 1024;

    f32x4 acc[4][4];
#pragma unroll
    for (int i = 0; i < 4; i++)
#pragma unroll
        for (int j = 0; j < 4; j++) acc[i][j] = (f32x4){0.f, 0.f, 0.f, 0.f};

    const int sr = tid >> 2;
    const int sc = (tid & 3) * 8;

    for (int k0 = 0; k0 < K; k0 += 32) {
        async_copy16(A + (size_t)(m0 + sr) * K + k0 + sc,       lA + sr * 32 + sc);
        async_copy16(A + (size_t)(m0 + 64 + sr) * K + k0 + sc,  lA + (64 + sr) * 32 + sc);
        async_copy16(W + (size_t)(n0 + sr) * K + k0 + sc,       lW + sr * 32 + sc);
        async_copy16(W + (size_t)(n0 + 64 + sr) * K + k0 + sc,  lW + (64 + sr) * 32 + sc);
        __syncthreads();

        bf16x8 af[4], bfr[4];
#pragma unroll
        for (int i = 0; i < 4; i++)
            af[i] = ld8(lA + (wm + i * 16 + lo) * 32 + quad * 8);
#pragma unroll
        for (int j = 0; j < 4; j++)
            bfr[j] = ld8(lW + (wn + j * 16 + lo) * 32 + quad * 8);
#pragma unroll
        for (int i = 0; i < 4; i++)
#pragma unroll
            for (int j = 0; j < 4; j++)
                acc[i][j] = __builtin_amdgcn_mfma_f32_16x16x32_bf16(af[i], bfr[j], acc[i][j], 0, 0, 0);
        __syncthreads();
    }

#pragma unroll
    for (int i = 0; i < 4; i++)
#pragma unroll
        for (int j = 0; j < 4; j++)
#pragma unroll
            for (int r = 0; r < 4; r++) {
                int m = m0 + wm + i * 16 + quad * 4 + r;
                int n = n0 + wn + j * 16 + lo;
                out[(size_t)m * D_ + n] = acc[i][j][r];
            }
}

// ---------------- attention ----------------
// Transposed flash attention, causal, no-max softmax.
// 128-thread blocks: 2 waves KV-split one 64-row q-chunk (flash-decoding
// style). No-max softmax => partials merge by pure addition (O=O0+O1,
// l=l0+l1) through LDS — no rescale, no extra global traffic.
// Per wave: 4 Q-subtiles share each K/V tile (32 MFMA / 8 loads).
__global__ __launch_bounds__(128) void attn(const bf16* __restrict__ Q,
                                            const bf16* __restrict__ K,
                                            const bf16* __restrict__ Vt,
                                            bf16* __restrict__ X) {
    __shared__ f32x4 sO[4][4][64];   // 16 KB: wave1 partial output
    __shared__ float sL[4][64];      // 1 KB: wave1 partial lsum (per-lane)
    const int tid  = threadIdx.x;
    const int wid  = tid >> 6;
    const int lane = tid & 63;
    const int quad = lane >> 4;
    const int lo   = lane & 15;
    const int idx  = blockIdx.x;
    const int bh   = idx & 63;          // XCD locality: one head stays on one XCD
    const int qbp  = 31 - (idx >> 6);   // LPT: longest q-blocks dispatched first
    const int q0   = qbp * 64;

    const bf16* Qp = Q  + (size_t)bh * S_ * DK_;
    const bf16* Kp = K  + (size_t)bh * S_ * DK_;
    const bf16* Vp = Vt + (size_t)bh * DK_ * S_;

    // 4 Q-subtiles of 16 rows each: rows q0 + qs*16 + lo
    bf16x8 bQ[4][2];
#pragma unroll
    for (int qs = 0; qs < 4; qs++) {
        const bf16* qp = Qp + (size_t)(q0 + qs * 16 + lo) * DK_ + quad * 8;
        bQ[qs][0] = ld8(qp);
        bQ[qs][1] = ld8(qp + 32);
    }

    f32x4 out[4][4];      // [q-subtile][dk-frag]
    float lsum[4] = {0.f, 0.f, 0.f, 0.f};
#pragma unroll
    for (int qs = 0; qs < 4; qs++)
#pragma unroll
        for (int t = 0; t < 4; t++) out[qs][t] = (f32x4){0.f, 0.f, 0.f, 0.f};

    const int NT   = 2 * qbp + 2;       // kv tiles (even); last two diagonal-ish
    const int half = NT >> 1;
    const int it0  = wid * half;        // wave0: [0,half), wave1: [half,NT)
    const int it1  = it0 + half;
    const int srcl = (quad & 1) * 32 + lo;
    const bool loT = (quad < 2);

    bf16x8 aK0, aK1, aK2, aK3;
    {
        const bf16* kn = Kp + (size_t)(it0 * 32 + lo) * DK_ + quad * 8;
        aK0 = ld8(kn); aK1 = ld8(kn + 32);
        aK2 = ld8(kn + 16 * DK_); aK3 = ld8(kn + 16 * DK_ + 32);
    }

    for (int it = it0; it < it1; ++it) {
        const int kv0 = it * 32;
        // mode per 32-row pair: 0=full, 1=diagonal, 2=killed
        const int am = (it < 2 * qbp) ? 0 : (it == 2 * qbp ? 1 : 2);
        const int bm = (it < 2 * qbp + 1) ? 0 : 1;

        bf16x8 aV[4];
#pragma unroll
        for (int t = 0; t < 4; t++)
            aV[t] = ld8(Vp + (size_t)(t * 16 + lo) * S_ + kv0 + quad * 8);

        // QK^T: 16 MFMA, K frags shared across 4 Q-subtiles
        f32x4 st[4][2];
        __builtin_amdgcn_s_setprio(1);
#pragma unroll
        for (int qs = 0; qs < 4; qs++) {
            f32x4 t0 = (f32x4){0.f, 0.f, 0.f, 0.f};
            f32x4 t1 = (f32x4){0.f, 0.f, 0.f, 0.f};
            t0 = __builtin_amdgcn_mfma_f32_16x16x32_bf16(aK0, bQ[qs][0], t0, 0, 0, 0);
            t0 = __builtin_amdgcn_mfma_f32_16x16x32_bf16(aK1, bQ[qs][1], t0, 0, 0, 0);
            t1 = __builtin_amdgcn_mfma_f32_16x16x32_bf16(aK2, bQ[qs][0], t1, 0, 0, 0);
            t1 = __builtin_amdgcn_mfma_f32_16x16x32_bf16(aK3, bQ[qs][1], t1, 0, 0, 0);
            st[qs][0] = t0; st[qs][1] = t1;
        }
        __builtin_amdgcn_s_setprio(0);

        // prefetch next K tile (overwrites aK after last use above)
        {
            int kvn = it + 1; if (kvn >= it1) kvn = it1 - 1;
            const bf16* kn = Kp + (size_t)(kvn * 32 + lo) * DK_ + quad * 8;
            aK0 = ld8(kn); aK1 = ld8(kn + 32);
            aK2 = ld8(kn + 16 * DK_); aK3 = ld8(kn + 16 * DK_ + 32);
        }

        // softmax + transpose per 32-row pair (two independent chains each)
        bf16x8 bP[4];
#pragma unroll
        for (int pr = 0; pr < 2; pr++) {
            const int mode = pr == 0 ? am : bm;
            const int sl = pr * 2, sh = pr * 2 + 1;
            float pl0[4], pl1[4], ph0[4], ph1[4];
#pragma unroll
            for (int r = 0; r < 4; r++) {
                float el0 = EXP2(st[sl][0][r]);
                float el1 = EXP2(st[sl][1][r]);
                float eh0 = EXP2(st[sh][0][r]);
                float eh1 = EXP2(st[sh][1][r]);
                if (mode == 1) {
                    bool c = (quad * 4 + r) <= lo;
                    el0 = c ? el0 : 0.f;
                    el1 = 0.f;
                    eh1 = c ? eh1 : 0.f;
                } else if (mode == 2) {
                    el0 = 0.f; el1 = 0.f; eh0 = 0.f; eh1 = 0.f;
                }
                pl0[r] = el0; pl1[r] = el1; ph0[r] = eh0; ph1[r] = eh1;
                lsum[sl] += el0 + el1;
                lsum[sh] += eh0 + eh1;
            }
            bP[sl] = transpose_p(pl0, pl1, srcl, loT);
            bP[sh] = transpose_p(ph0, ph1, srcl, loT);
        }

        // PV: 16 MFMA, V frags shared across 4 P fragments
        __builtin_amdgcn_s_setprio(1);
#pragma unroll
        for (int qs = 0; qs < 4; qs++)
#pragma unroll
            for (int t = 0; t < 4; t++)
                out[qs][t] = __builtin_amdgcn_mfma_f32_16x16x32_bf16(aV[t], bP[qs], out[qs][t], 0, 0, 0);
        __builtin_amdgcn_s_setprio(0);
    }

    // merge wave1's partials into wave0 through LDS (pure add: no-max softmax)
    if (wid == 1) {
#pragma unroll
        for (int qs = 0; qs < 4; qs++) {
#pragma unroll
            for (int t = 0; t < 4; t++) sO[qs][t][lane] = out[qs][t];
            sL[qs][lane] = lsum[qs];
        }
    }
    __syncthreads();
    if (wid == 0) {
        const int b = bh >> 4, h = bh & 15;
#pragma unroll
        for (int qs = 0; qs < 4; qs++) {
#pragma unroll
            for (int t = 0; t < 4; t++) {
                f32x4 p = sO[qs][t][lane];
                out[qs][t][0] += p[0]; out[qs][t][1] += p[1];
                out[qs][t][2] += p[2]; out[qs][t][3] += p[3];
            }
            float ls = lsum[qs] + sL[qs][lane];
            ls += __shfl_xor(ls, 16, 64);
            ls += __shfl_xor(ls, 32, 64);
            const float rl = 1.f / ls;
            bf16* Xp = X + (size_t)(b * S_ + q0 + qs * 16 + lo) * D_ + h * 64;
#pragma unroll
            for (int t = 0; t < 4; t++) {
                uint32_t* d = (uint32_t*)(Xp + t * 16 + quad * 4);
                d[0] = pk2(out[qs][t][0] * rl, out[qs][t][1] * rl);
                d[1] = pk2(out[qs][t][2] * rl, out[qs][t][3] * rl);
            }
        }
    }
}

extern "C" void kernel_launch(void* const* d_in, const int* in_sizes, int n_in,
                              void* d_out, int out_size, void* d_ws, size_t ws_size,
                              hipStream_t stream) {
    const float* q  = (const float*)d_in[0];
    const float* k  = (const float*)d_in[1];
    const float* v  = (const float*)d_in[2];
    const float* wq = (const float*)d_in[4];
    const float* wk = (const float*)d_in[5];
    const float* wv = (const float*)d_in[6];
    const float* wo = (const float*)d_in[7];

    const size_t elems  = (size_t)B_ * S_ * D_;   // 8388608
    const size_t welems = (size_t)D_ * D_;        // 1048576
    // ws layout (bf16 elems):
    //   [Wo: 1M][Wq: 1M][Wk: 1M][Wv: 1M ... X region spans Wq..Wv+pad: 8M][Qw][Kw][Vw]
    //   (optionally) [Aqb][Akb][Avb] — bf16 copies of q,k,v for the pure-async GEMM.
    bf16* WoB = (bf16*)d_ws;            // elem 0
    bf16* WqB = WoB + welems;           // elem 1M
    bf16* WkB = WqB + welems;           // elem 2M
    bf16* WvB = WkB + welems;           // elem 3M
    bf16* Xb  = WqB;                    // elem 1M .. 1M+8M (aliases Wq/Wk/Wv by design)
    bf16* Qw  = WqB + elems;            // elem 1M+8M
    bf16* Kw  = Qw + elems;
    bf16* Vw  = Kw + elems;
    bf16* Aqb = Vw + elems;             // elem 33M (big-ws path only)
    bf16* Akb = Aqb + elems;
    bf16* Avb = Akb + elems;

    const size_t need_big = ((size_t)(Avb + elems) - (size_t)d_ws);  // 119.5 MB

    // 1. convert all four weight matrices (one launch)
    hipLaunchKernelGGL(cvtw, dim3(4 * (int)(welems / 4) / 256), dim3(256), 0, stream,
                       (const float4*)wq, (const float4*)wk, (const float4*)wv,
                       (const float4*)wo,
                       (bf16x4*)WqB, (bf16x4*)WkB, (bf16x4*)WvB, (bf16x4*)WoB);

    if (ws_size >= need_big) {
        // 2a. one-shot activation conversion, then pure-async bf16 QKV GEMM
        hipLaunchKernelGGL(cvtx, dim3((int)(elems / 8 / 256), 1, 3), dim3(256), 0, stream,
                           q, k, v, Aqb, Akb, Avb);
        hipLaunchKernelGGL(gemm_qkv_bf, dim3((B_ * S_) / 128, D_ / 128, 3), dim3(256), 0,
                           stream, Aqb, Akb, Avb, WqB, WkB, WvB, Qw, Kw, Vw);
    } else {
        // 2b. fallback: fused in-register conversion path
        hipLaunchKernelGGL(gemm_qkv, dim3((B_ * S_) / 128, D_ / 128, 3), dim3(256), 0,
                           stream, q, k, v, WqB, WkB, WvB, Qw, Kw, Vw);
    }

    // 3. attention: 128-thread blocks, 2 waves KV-split per 64-row q-chunk
    hipLaunchKernelGGL(attn, dim3((S_ / 64) * B_ * H_), dim3(128), 0, stream, Qw, Kw, Vw, Xb);
    // 4. output projection -> d_out (f32)
    hipLaunchKernelGGL(gemm_out, dim3((B_ * S_) / 128, D_ / 128), dim3(256), 0, stream,
                       Xb, WoB, (float*)d_out);
}

// Round 8
// 342.837 us; speedup vs baseline: 1.3034x; 1.0056x over previous
//
#include <hip/hip_runtime.h>
#include <hip/hip_bf16.h>
#include <stdint.h>

#define B_ 4
#define S_ 2048
#define D_ 1024
#define H_ 16
#define DK_ 64

typedef __hip_bfloat16 bf16;
typedef __attribute__((ext_vector_type(8))) __bf16 bf16x8;
typedef __attribute__((ext_vector_type(4))) __bf16 bf16x4;
typedef __attribute__((ext_vector_type(4))) float f32x4;
typedef __attribute__((ext_vector_type(4))) uint32_t u32x4;

// scale 1/sqrt(DK) folded with log2(e): Q pre-scaled so p = exp2(S^T) directly
#define QSCALE 0.18033688011112042f   // 0.125 * 1.4426950408889634

#if defined(__has_builtin)
#if __has_builtin(__builtin_amdgcn_exp2f)
#define EXP2(x) __builtin_amdgcn_exp2f(x)
#endif
#endif
#ifndef EXP2
#define EXP2(x) exp2f(x)
#endif

__device__ __forceinline__ void async_copy16(const void* g, void* l) {
    __builtin_amdgcn_global_load_lds((const __attribute__((address_space(1))) void*)g,
                                     (__attribute__((address_space(3))) void*)l,
                                     16, 0, 0);
}

__device__ __forceinline__ bf16x8 ld8(const bf16* p) {
    return *(const bf16x8*)p;
}

__device__ __forceinline__ uint32_t pk2(float a, float b) {
    union { __bf16 h; uint16_t u; } x, y;
    x.h = (__bf16)a; y.h = (__bf16)b;
    return (uint32_t)x.u | ((uint32_t)y.u << 16);
}

__device__ __forceinline__ bf16x8 cvt8(float4 u0, float4 u1) {
    return (bf16x8){(__bf16)u0.x, (__bf16)u0.y, (__bf16)u0.z, (__bf16)u0.w,
                    (__bf16)u1.x, (__bf16)u1.y, (__bf16)u1.z, (__bf16)u1.w};
}

// C-layout 16x32 P-tile (two 16x16 subtiles p0,p1) -> B-fragment of P^T (k=32, n=16)
__device__ __forceinline__ bf16x8 transpose_p(const float* p0, const float* p1,
                                              int srcl, bool loT) {
    uint32_t x0 = pk2(p0[0], p0[1]), x1 = pk2(p0[2], p0[3]);
    uint32_t y0 = pk2(p1[0], p1[1]), y1 = pk2(p1[2], p1[3]);
    u32x4 dw;
#pragma unroll
    for (int i = 0; i < 4; i++) {
        int sl = srcl + (i >> 1) * 16;
        uint32_t vA = (uint32_t)__shfl((int)((i & 1) ? x1 : x0), sl, 64);
        uint32_t vB = (uint32_t)__shfl((int)((i & 1) ? y1 : y0), sl, 64);
        dw[i] = loT ? vA : vB;
    }
    return __builtin_bit_cast(bf16x8, dw);
}

// convert the 4 weight matrices f32->bf16 in one launch (4 x 262144 float4)
__global__ __launch_bounds__(256) void cvtw(const float4* __restrict__ s0,
                                            const float4* __restrict__ s1,
                                            const float4* __restrict__ s2,
                                            const float4* __restrict__ s3,
                                            bf16x4* __restrict__ d0,
                                            bf16x4* __restrict__ d1,
                                            bf16x4* __restrict__ d2,
                                            bf16x4* __restrict__ d3) {
    int i = blockIdx.x * 256 + threadIdx.x;
    int seg = i >> 18;            // 262144 float4 per matrix
    int j   = i & 262143;
    const float4* s = seg == 0 ? s0 : seg == 1 ? s1 : seg == 2 ? s2 : s3;
    bf16x4*       d = seg == 0 ? d0 : seg == 1 ? d1 : seg == 2 ? d2 : d3;
    float4 f = s[j];
    d[j] = (bf16x4){(__bf16)f.x, (__bf16)f.y, (__bf16)f.z, (__bf16)f.w};
}

// one-shot activation conversion f32 -> bf16 (q,k,v), 8 elems / thread
__global__ __launch_bounds__(256) void cvtx(const float* __restrict__ s0,
                                            const float* __restrict__ s1,
                                            const float* __restrict__ s2,
                                            bf16* __restrict__ d0,
                                            bf16* __restrict__ d1,
                                            bf16* __restrict__ d2) {
    const int z = blockIdx.z;
    const float* s = z == 0 ? s0 : z == 1 ? s1 : s2;
    bf16*        d = z == 0 ? d0 : z == 1 ? d1 : d2;
    size_t i = ((size_t)blockIdx.x * 256 + threadIdx.x) * 8;
    float4 u0 = *(const float4*)(s + i);
    float4 u1 = *(const float4*)(s + i + 4);
    *(bf16x8*)(d + i) = cvt8(u0, u1);
}

// Pure-bf16 fused Q/K/V projection.
// Grid (m=64, n=8, z=3): XCD = m-tile%8 -> A panels single-XCD (r5 win).
// K-loop: T3 minimum 2-phase pipeline — double-buffered LDS, one raw
// s_barrier per K-step, vmcnt(0) drained AFTER the MFMA cluster so the
// next tile's global_load_lds latency hides under compute.
__global__ __launch_bounds__(256) void gemm_qkv_bf(const bf16* __restrict__ Aq,
                                                   const bf16* __restrict__ Ak,
                                                   const bf16* __restrict__ Av,
                                                   const bf16* __restrict__ Wqb,
                                                   const bf16* __restrict__ Wkb,
                                                   const bf16* __restrict__ Wvb,
                                                   bf16* __restrict__ Oq,
                                                   bf16* __restrict__ Ok,
                                                   bf16* __restrict__ Ov) {
    __shared__ bf16 lA[2][128 * 32];
    __shared__ bf16 lW[2][128 * 32];
    const int z = blockIdx.z;
    const bf16* A = z == 0 ? Aq : z == 1 ? Ak : Av;
    const bf16* W = z == 0 ? Wqb : z == 1 ? Wkb : Wvb;
    bf16*      out = z == 0 ? Oq : z == 1 ? Ok : Ov;

    const int tid  = threadIdx.x;
    const int lane = tid & 63;
    const int quad = lane >> 4;
    const int lo   = lane & 15;
    const int wave = tid >> 6;
    const int wm   = (wave >> 1) * 64;
    const int wn   = (wave & 1) * 64;
    const int n0   = blockIdx.y * 128;
    const int m0   = blockIdx.x * 128;
    const int K    = 1024;

    f32x4 acc[4][4];
#pragma unroll
    for (int i = 0; i < 4; i++)
#pragma unroll
        for (int j = 0; j < 4; j++) acc[i][j] = (f32x4){0.f, 0.f, 0.f, 0.f};

    const int sr = tid >> 2;
    const int sc = (tid & 3) * 8;

    // prologue: stage tile 0 into buffer 0, full drain, sync
    async_copy16(A + (size_t)(m0 + sr) * K + sc,       lA[0] + sr * 32 + sc);
    async_copy16(A + (size_t)(m0 + 64 + sr) * K + sc,  lA[0] + (64 + sr) * 32 + sc);
    async_copy16(W + (size_t)(n0 + sr) * K + sc,       lW[0] + sr * 32 + sc);
    async_copy16(W + (size_t)(n0 + 64 + sr) * K + sc,  lW[0] + (64 + sr) * 32 + sc);
    asm volatile("s_waitcnt vmcnt(0)" ::: "memory");
    __builtin_amdgcn_s_barrier();
    __builtin_amdgcn_sched_barrier(0);

    for (int t = 0; t < 32; ++t) {
        const int cur = t & 1;
        bf16* cA = lA[cur];
        bf16* cW = lW[cur];
        if (t < 31) {
            const int kn = (t + 1) * 32;
            bf16* nA = lA[cur ^ 1];
            bf16* nW = lW[cur ^ 1];
            async_copy16(A + (size_t)(m0 + sr) * K + kn + sc,       nA + sr * 32 + sc);
            async_copy16(A + (size_t)(m0 + 64 + sr) * K + kn + sc,  nA + (64 + sr) * 32 + sc);
            async_copy16(W + (size_t)(n0 + sr) * K + kn + sc,       nW + sr * 32 + sc);
            async_copy16(W + (size_t)(n0 + 64 + sr) * K + kn + sc,  nW + (64 + sr) * 32 + sc);
        }

        bf16x8 af[4], bfr[4];
#pragma unroll
        for (int i = 0; i < 4; i++)
            af[i] = ld8(cA + (wm + i * 16 + lo) * 32 + quad * 8);
#pragma unroll
        for (int j = 0; j < 4; j++)
            bfr[j] = ld8(cW + (wn + j * 16 + lo) * 32 + quad * 8);
        asm volatile("s_waitcnt lgkmcnt(0)" ::: "memory");
        __builtin_amdgcn_sched_barrier(0);

        __builtin_amdgcn_s_setprio(1);
#pragma unroll
        for (int i = 0; i < 4; i++)
#pragma unroll
            for (int j = 0; j < 4; j++)
                acc[i][j] = __builtin_amdgcn_mfma_f32_16x16x32_bf16(af[i], bfr[j], acc[i][j], 0, 0, 0);
        __builtin_amdgcn_s_setprio(0);

        asm volatile("s_waitcnt vmcnt(0)" ::: "memory");   // next tile fully landed
        __builtin_amdgcn_s_barrier();                       // all waves done reading cur
        __builtin_amdgcn_sched_barrier(0);
    }

#pragma unroll
    for (int i = 0; i < 4; i++)
#pragma unroll
        for (int j = 0; j < 4; j++)
#pragma unroll
            for (int r = 0; r < 4; r++) {
                int m = m0 + wm + i * 16 + quad * 4 + r;
                int n = n0 + wn + j * 16 + lo;
                float val = acc[i][j][r];
                int b = m >> 11, s = m & (S_ - 1);
                int h = n >> 6, dk = n & 63;
                if (z == 0) {
                    out[((size_t)(b * H_ + h) * S_ + s) * DK_ + dk] =
                        __float2bfloat16(val * QSCALE);
                } else if (z == 1) {
                    out[((size_t)(b * H_ + h) * S_ + s) * DK_ + dk] = __float2bfloat16(val);
                } else {
                    out[((size_t)(b * H_ + h) * DK_ + dk) * S_ + s] = __float2bfloat16(val);
                }
            }
}

// Fallback (small workspace): fused in-register f32->bf16 conversion path.
__global__ __launch_bounds__(256) void gemm_qkv(const float* __restrict__ Aq,
                                                const float* __restrict__ Ak,
                                                const float* __restrict__ Av,
                                                const bf16* __restrict__ Wqb,
                                                const bf16* __restrict__ Wkb,
                                                const bf16* __restrict__ Wvb,
                                                bf16* __restrict__ Oq,
                                                bf16* __restrict__ Ok,
                                                bf16* __restrict__ Ov) {
    __shared__ bf16 lA[128 * 32];
    __shared__ bf16 lW[128 * 32];
    const int z = blockIdx.z;
    const float* A = z == 0 ? Aq : z == 1 ? Ak : Av;
    const bf16*  W = z == 0 ? Wqb : z == 1 ? Wkb : Wvb;
    bf16*      out = z == 0 ? Oq : z == 1 ? Ok : Ov;

    const int tid  = threadIdx.x;
    const int lane = tid & 63;
    const int quad = lane >> 4;
    const int lo   = lane & 15;
    const int wave = tid >> 6;
    const int wm   = (wave >> 1) * 64;
    const int wn   = (wave & 1) * 64;
    const int n0   = blockIdx.y * 128;
    const int m0   = blockIdx.x * 128;
    const int K    = 1024;

    f32x4 acc[4][4];
#pragma unroll
    for (int i = 0; i < 4; i++)
#pragma unroll
        for (int j = 0; j < 4; j++) acc[i][j] = (f32x4){0.f, 0.f, 0.f, 0.f};

    const int sr = tid >> 2;
    const int sc = (tid & 3) * 8;

    for (int k0 = 0; k0 < K; k0 += 32) {
        async_copy16(W + (size_t)(n0 + sr) * K + k0 + sc,       lW + sr * 32 + sc);
        async_copy16(W + (size_t)(n0 + 64 + sr) * K + k0 + sc,  lW + (64 + sr) * 32 + sc);
        const float* a0 = A + (size_t)(m0 + sr) * K + k0 + sc;
        const float* a1 = A + (size_t)(m0 + 64 + sr) * K + k0 + sc;
        float4 u0 = *(const float4*)a0;
        float4 u1 = *(const float4*)(a0 + 4);
        float4 u2 = *(const float4*)a1;
        float4 u3 = *(const float4*)(a1 + 4);
        *(bf16x8*)(lA + sr * 32 + sc)        = cvt8(u0, u1);
        *(bf16x8*)(lA + (64 + sr) * 32 + sc) = cvt8(u2, u3);
        __syncthreads();

        bf16x8 af[4], bfr[4];
#pragma unroll
        for (int i = 0; i < 4; i++)
            af[i] = ld8(lA + (wm + i * 16 + lo) * 32 + quad * 8);
#pragma unroll
        for (int j = 0; j < 4; j++)
            bfr[j] = ld8(lW + (wn + j * 16 + lo) * 32 + quad * 8);
#pragma unroll
        for (int i = 0; i < 4; i++)
#pragma unroll
            for (int j = 0; j < 4; j++)
                acc[i][j] = __builtin_amdgcn_mfma_f32_16x16x32_bf16(af[i], bfr[j], acc[i][j], 0, 0, 0);
        __syncthreads();
    }

#pragma unroll
    for (int i = 0; i < 4; i++)
#pragma unroll
        for (int j = 0; j < 4; j++)
#pragma unroll
            for (int r = 0; r < 4; r++) {
                int m = m0 + wm + i * 16 + quad * 4 + r;
                int n = n0 + wn + j * 16 + lo;
                float val = acc[i][j][r];
                int b = m >> 11, s = m & (S_ - 1);
                int h = n >> 6, dk = n & 63;
                if (z == 0) {
                    out[((size_t)(b * H_ + h) * S_ + s) * DK_ + dk] =
                        __float2bfloat16(val * QSCALE);
                } else if (z == 1) {
                    out[((size_t)(b * H_ + h) * S_ + s) * DK_ + dk] = __float2bfloat16(val);
                } else {
                    out[((size_t)(b * H_ + h) * DK_ + dk) * S_ + s] = __float2bfloat16(val);
                }
            }
}

// Final projection: A bf16 (attn output X), W bf16, out float32 [8192 x 1024]
// Grid (m=64, n=8); same 2-phase pipelined K-loop as gemm_qkv_bf.
__global__ __launch_bounds__(256) void gemm_out(const bf16* __restrict__ A,
                                                const bf16* __restrict__ W,
                                                float* __restrict__ out) {
    __shared__ bf16 lA[2][128 * 32];
    __shared__ bf16 lW[2][128 * 32];
    const int tid  = threadIdx.x;
    const int lane = tid & 63;
    const int quad = lane >> 4;
    const int lo   = lane & 15;
    const int wave = tid >> 6;
    const int wm   = (wave >> 1) * 64;
    const int wn   = (wave & 1) * 64;
    const int n0   = blockIdx.y * 128;
    const int m0   = blockIdx.x * 128;
    const int K    = 1024;

    f32x4 acc[4][4];
#pragma unroll
    for (int i = 0; i < 4; i++)
#pragma unroll
        for (int j = 0; j < 4; j++) acc[i][j] = (f32x4){0.f, 0.f, 0.f, 0.f};

    const int sr = tid >> 2;
    const int sc = (tid & 3) * 8;

    async_copy16(A + (size_t)(m0 + sr) * K + sc,       lA[0] + sr * 32 + sc);
    async_copy16(A + (size_t)(m0 + 64 + sr) * K + sc,  lA[0] + (64 + sr) * 32 + sc);
    async_copy16(W + (size_t)(n0 + sr) * K + sc,       lW[0] + sr * 32 + sc);
    async_copy16(W + (size_t)(n0 + 64 + sr) * K + sc,  lW[0] + (64 + sr) * 32 + sc);
    asm volatile("s_waitcnt vmcnt(0)" ::: "memory");
    __builtin_amdgcn_s_barrier();
    __builtin_amdgcn_sched_barrier(0);

    for (int t = 0; t < 32; ++t) {
        const int cur = t & 1;
        bf16* cA = lA[cur];
        bf16* cW = lW[cur];
        if (t < 31) {
            const int kn = (t + 1) * 32;
            bf16* nA = lA[cur ^ 1];
            bf16* nW = lW[cur ^ 1];
            async_copy16(A + (size_t)(m0 + sr) * K + kn + sc,       nA + sr * 32 + sc);
            async_copy16(A + (size_t)(m0 + 64 + sr) * K + kn + sc,  nA + (64 + sr) * 32 + sc);
            async_copy16(W + (size_t)(n0 + sr) * K + kn + sc,       nW + sr * 32 + sc);
            async_copy16(W + (size_t)(n0 + 64 + sr) * K + kn + sc,  nW + (64 + sr) * 32 + sc);
        }

        bf16x8 af[4], bfr[4];
#pragma unroll
        for (int i = 0; i < 4; i++)
            af[i] = ld8(cA + (wm + i * 16 + lo) * 32 + quad * 8);
#pragma unroll
        for (int j = 0; j < 4; j++)
            bfr[j] = ld8(cW + (wn + j * 16 + lo) * 32 + quad * 8);
        asm volatile("s_waitcnt lgkmcnt(0)" ::: "memory");
        __builtin_amdgcn_sched_barrier(0);

        __builtin_amdgcn_s_setprio(1);
#pragma unroll
        for (int i = 0; i < 4; i++)
#pragma unroll
            for (int j = 0; j < 4; j++)
                acc[i][j] = __builtin_amdgcn_mfma_f32_16x16x32_bf16(af[i], bfr[j], acc[i][j], 0, 0, 0);
        __builtin_amdgcn_s_setprio(0);

        asm volatile("s_waitcnt vmcnt(0)" ::: "memory");
        __builtin_amdgcn_s_barrier();
        __builtin_amdgcn_sched_barrier(0);
    }

#pragma unroll
    for (int i = 0; i < 4; i++)
#pragma unroll
        for (int j = 0; j < 4; j++)
#pragma unroll
            for (int r = 0; r < 4; r++) {
                int m = m0 + wm + i * 16 + quad * 4 + r;
                int n = n0 + wn + j * 16 + lo;
                out[(size_t)m * D_ + n] = acc[i][j][r];
            }
}

// ---------------- attention ----------------
// Transposed flash attention, causal, no-max softmax.
// 128-thread blocks: 2 waves KV-split one 64-row q-chunk (flash-decoding
// style). No-max softmax => partials merge by pure addition (O=O0+O1,
// l=l0+l1) through LDS — no rescale, no extra global traffic.
// Per wave: 4 Q-subtiles share each K/V tile (32 MFMA / 8 loads).
__global__ __launch_bounds__(128) void attn(const bf16* __restrict__ Q,
                                            const bf16* __restrict__ K,
                                            const bf16* __restrict__ Vt,
                                            bf16* __restrict__ X) {
    __shared__ f32x4 sO[4][4][64];   // 16 KB: wave1 partial output
    __shared__ float sL[4][64];      // 1 KB: wave1 partial lsum (per-lane)
    const int tid  = threadIdx.x;
    const int wid  = tid >> 6;
    const int lane = tid & 63;
    const int quad = lane >> 4;
    const int lo   = lane & 15;
    const int idx  = blockIdx.x;
    const int bh   = idx & 63;          // XCD locality: one head stays on one XCD
    const int qbp  = 31 - (idx >> 6);   // LPT: longest q-blocks dispatched first
    const int q0   = qbp * 64;

    const bf16* Qp = Q  + (size_t)bh * S_ * DK_;
    const bf16* Kp = K  + (size_t)bh * S_ * DK_;
    const bf16* Vp = Vt + (size_t)bh * DK_ * S_;

    // 4 Q-subtiles of 16 rows each: rows q0 + qs*16 + lo
    bf16x8 bQ[4][2];
#pragma unroll
    for (int qs = 0; qs < 4; qs++) {
        const bf16* qp = Qp + (size_t)(q0 + qs * 16 + lo) * DK_ + quad * 8;
        bQ[qs][0] = ld8(qp);
        bQ[qs][1] = ld8(qp + 32);
    }

    f32x4 out[4][4];      // [q-subtile][dk-frag]
    float lsum[4] = {0.f, 0.f, 0.f, 0.f};
#pragma unroll
    for (int qs = 0; qs < 4; qs++)
#pragma unroll
        for (int t = 0; t < 4; t++) out[qs][t] = (f32x4){0.f, 0.f, 0.f, 0.f};

    const int NT   = 2 * qbp + 2;       // kv tiles (even); last two diagonal-ish
    const int half = NT >> 1;
    const int it0  = wid * half;        // wave0: [0,half), wave1: [half,NT)
    const int it1  = it0 + half;
    const int srcl = (quad & 1) * 32 + lo;
    const bool loT = (quad < 2);

    bf16x8 aK0, aK1, aK2, aK3;
    {
        const bf16* kn = Kp + (size_t)(it0 * 32 + lo) * DK_ + quad * 8;
        aK0 = ld8(kn); aK1 = ld8(kn + 32);
        aK2 = ld8(kn + 16 * DK_); aK3 = ld8(kn + 16 * DK_ + 32);
    }

    for (int it = it0; it < it1; ++it) {
        const int kv0 = it * 32;
        // mode per 32-row pair: 0=full, 1=diagonal, 2=killed
        const int am = (it < 2 * qbp) ? 0 : (it == 2 * qbp ? 1 : 2);
        const int bm = (it < 2 * qbp + 1) ? 0 : 1;

        bf16x8 aV[4];
#pragma unroll
        for (int t = 0; t < 4; t++)
            aV[t] = ld8(Vp + (size_t)(t * 16 + lo) * S_ + kv0 + quad * 8);

        // QK^T: 16 MFMA, K frags shared across 4 Q-subtiles
        f32x4 st[4][2];
        __builtin_amdgcn_s_setprio(1);
#pragma unroll
        for (int qs = 0; qs < 4; qs++) {
            f32x4 t0 = (f32x4){0.f, 0.f, 0.f, 0.f};
            f32x4 t1 = (f32x4){0.f, 0.f, 0.f, 0.f};
            t0 = __builtin_amdgcn_mfma_f32_16x16x32_bf16(aK0, bQ[qs][0], t0, 0, 0, 0);
            t0 = __builtin_amdgcn_mfma_f32_16x16x32_bf16(aK1, bQ[qs][1], t0, 0, 0, 0);
            t1 = __builtin_amdgcn_mfma_f32_16x16x32_bf16(aK2, bQ[qs][0], t1, 0, 0, 0);
            t1 = __builtin_amdgcn_mfma_f32_16x16x32_bf16(aK3, bQ[qs][1], t1, 0, 0, 0);
            st[qs][0] = t0; st[qs][1] = t1;
        }
        __builtin_amdgcn_s_setprio(0);

        // prefetch next K tile (overwrites aK after last use above)
        {
            int kvn = it + 1; if (kvn >= it1) kvn = it1 - 1;
            const bf16* kn = Kp + (size_t)(kvn * 32 + lo) * DK_ + quad * 8;
            aK0 = ld8(kn); aK1 = ld8(kn + 32);
            aK2 = ld8(kn + 16 * DK_); aK3 = ld8(kn + 16 * DK_ + 32);
        }

        // softmax + transpose per 32-row pair (two independent chains each)
        bf16x8 bP[4];
#pragma unroll
        for (int pr = 0; pr < 2; pr++) {
            const int mode = pr == 0 ? am : bm;
            const int sl = pr * 2, sh = pr * 2 + 1;
            float pl0[4], pl1[4], ph0[4], ph1[4];
#pragma unroll
            for (int r = 0; r < 4; r++) {
                float el0 = EXP2(st[sl][0][r]);
                float el1 = EXP2(st[sl][1][r]);
                float eh0 = EXP2(st[sh][0][r]);
                float eh1 = EXP2(st[sh][1][r]);
                if (mode == 1) {
                    bool c = (quad * 4 + r) <= lo;
                    el0 = c ? el0 : 0.f;
                    el1 = 0.f;
                    eh1 = c ? eh1 : 0.f;
                } else if (mode == 2) {
                    el0 = 0.f; el1 = 0.f; eh0 = 0.f; eh1 = 0.f;
                }
                pl0[r] = el0; pl1[r] = el1; ph0[r] = eh0; ph1[r] = eh1;
                lsum[sl] += el0 + el1;
                lsum[sh] += eh0 + eh1;
            }
            bP[sl] = transpose_p(pl0, pl1, srcl, loT);
            bP[sh] = transpose_p(ph0, ph1, srcl, loT);
        }

        // PV: 16 MFMA, V frags shared across 4 P fragments
        __builtin_amdgcn_s_setprio(1);
#pragma unroll
        for (int qs = 0; qs < 4; qs++)
#pragma unroll
            for (int t = 0; t < 4; t++)
                out[qs][t] = __builtin_amdgcn_mfma_f32_16x16x32_bf16(aV[t], bP[qs], out[qs][t], 0, 0, 0);
        __builtin_amdgcn_s_setprio(0);
    }

    // merge wave1's partials into wave0 through LDS (pure add: no-max softmax)
    if (wid == 1) {
#pragma unroll
        for (int qs = 0; qs < 4; qs++) {
#pragma unroll
            for (int t = 0; t < 4; t++) sO[qs][t][lane] = out[qs][t];
            sL[qs][lane] = lsum[qs];
        }
    }
    __syncthreads();
    if (wid == 0) {
        const int b = bh >> 4, h = bh & 15;
#pragma unroll
        for (int qs = 0; qs < 4; qs++) {
#pragma unroll
            for (int t = 0; t < 4; t++) {
                f32x4 p = sO[qs][t][lane];
                out[qs][t][0] += p[0]; out[qs][t][1] += p[1];
                out[qs][t][2] += p[2]; out[qs][t][3] += p[3];
            }
            float ls = lsum[qs] + sL[qs][lane];
            ls += __shfl_xor(ls, 16, 64);
            ls += __shfl_xor(ls, 32, 64);
            const float rl = 1.f / ls;
            bf16* Xp = X + (size_t)(b * S_ + q0 + qs * 16 + lo) * D_ + h * 64;
#pragma unroll
            for (int t = 0; t < 4; t++) {
                uint32_t* d = (uint32_t*)(Xp + t * 16 + quad * 4);
                d[0] = pk2(out[qs][t][0] * rl, out[qs][t][1] * rl);
                d[1] = pk2(out[qs][t][2] * rl, out[qs][t][3] * rl);
            }
        }
    }
}

extern "C" void kernel_launch(void* const* d_in, const int* in_sizes, int n_in,
                              void* d_out, int out_size, void* d_ws, size_t ws_size,
                              hipStream_t stream) {
    const float* q  = (const float*)d_in[0];
    const float* k  = (const float*)d_in[1];
    const float* v  = (const float*)d_in[2];
    const float* wq = (const float*)d_in[4];
    const float* wk = (const float*)d_in[5];
    const float* wv = (const float*)d_in[6];
    const float* wo = (const float*)d_in[7];

    const size_t elems  = (size_t)B_ * S_ * D_;   // 8388608
    const size_t welems = (size_t)D_ * D_;        // 1048576
    // ws layout (bf16 elems):
    //   [Wo: 1M][Wq: 1M][Wk: 1M][Wv: 1M ... X region spans Wq..Wv+pad: 8M][Qw][Kw][Vw]
    //   (optionally) [Aqb][Akb][Avb] — bf16 copies of q,k,v for the pure-async GEMM.
    bf16* WoB = (bf16*)d_ws;            // elem 0
    bf16* WqB = WoB + welems;           // elem 1M
    bf16* WkB = WqB + welems;           // elem 2M
    bf16* WvB = WkB + welems;           // elem 3M
    bf16* Xb  = WqB;                    // elem 1M .. 1M+8M (aliases Wq/Wk/Wv by design)
    bf16* Qw  = WqB + elems;            // elem 1M+8M
    bf16* Kw  = Qw + elems;
    bf16* Vw  = Kw + elems;
    bf16* Aqb = Vw + elems;             // elem 33M (big-ws path only)
    bf16* Akb = Aqb + elems;
    bf16* Avb = Akb + elems;

    const size_t need_big = ((size_t)(Avb + elems) - (size_t)d_ws);  // 119.5 MB

    // 1. convert all four weight matrices (one launch)
    hipLaunchKernelGGL(cvtw, dim3(4 * (int)(welems / 4) / 256), dim3(256), 0, stream,
                       (const float4*)wq, (const float4*)wk, (const float4*)wv,
                       (const float4*)wo,
                       (bf16x4*)WqB, (bf16x4*)WkB, (bf16x4*)WvB, (bf16x4*)WoB);

    if (ws_size >= need_big) {
        // 2a. one-shot activation conversion, then pure-async bf16 QKV GEMM
        hipLaunchKernelGGL(cvtx, dim3((int)(elems / 8 / 256), 1, 3), dim3(256), 0, stream,
                           q, k, v, Aqb, Akb, Avb);
        hipLaunchKernelGGL(gemm_qkv_bf, dim3((B_ * S_) / 128, D_ / 128, 3), dim3(256), 0,
                           stream, Aqb, Akb, Avb, WqB, WkB, WvB, Qw, Kw, Vw);
    } else {
        // 2b. fallback: fused in-register conversion path
        hipLaunchKernelGGL(gemm_qkv, dim3((B_ * S_) / 128, D_ / 128, 3), dim3(256), 0,
                           stream, q, k, v, WqB, WkB, WvB, Qw, Kw, Vw);
    }

    // 3. attention: 128-thread blocks, 2 waves KV-split per 64-row q-chunk
    hipLaunchKernelGGL(attn, dim3((S_ / 64) * B_ * H_), dim3(128), 0, stream, Qw, Kw, Vw, Xb);
    // 4. output projection -> d_out (f32)
    hipLaunchKernelGGL(gemm_out, dim3((B_ * S_) / 128, D_ / 128), dim3(256), 0, stream,
                       Xb, WoB, (float*)d_out);
}